// Round 8
// baseline (1084.999 us; speedup 1.0000x reference)
//
#include <hip/hip_runtime.h>
#include <math.h>

// Problem constants
#define B_    256
#define N_    128
#define F_    133
#define H_    8
#define ND_   64     // NHID
#define HID_  300
#define FPD_  1489
#define FP2_  512
#define ALPHA_ 0.2f
#define NEG_  -9.0e15f

__device__ __forceinline__ float wred_sum(float v) {
#pragma unroll
  for (int m = 32; m >= 1; m >>= 1) v += __shfl_xor(v, m, 64);
  return v;
}
__device__ __forceinline__ float wred_max(float v) {
#pragma unroll
  for (int m = 32; m >= 1; m >>= 1) v = fmaxf(v, __shfl_xor(v, m, 64));
  return v;
}
__device__ __forceinline__ float lrelu(float x) { return x > 0.f ? x : ALPHA_ * x; }
__device__ __forceinline__ float eluf(float x)  { return x > 0.f ? x : expf(x) - 1.f; }
__device__ __forceinline__ float rdlane(float v, int l) {
  return __int_as_float(__builtin_amdgcn_readlane(__float_as_int(v), l));
}
// 16B load at 4B alignment (safe form)
__device__ __forceinline__ float4 ld4u(const float* p) {
  float4 v;
  __builtin_memcpy(&v, p, 16);
  return v;
}

// K1: Wh[b,h,n,d] = sum_f A[b,n,f] * W[h,f,d];  s/d projections fused.
// grid 2048, block 512 (8 waves; wave = head h, lane = d). 16 rows/block.
__global__ __launch_bounds__(512) void k1_wh(
    const float* __restrict__ A, const float* __restrict__ W,
    const float* __restrict__ ah, float* __restrict__ Wh,
    float* __restrict__ sb, float* __restrict__ db) {
  __shared__ __align__(16) float As[16 * 136];
  const int tid = threadIdx.x;
  const int lane = tid & 63;
  const int h = tid >> 6;
  const int m0 = blockIdx.x * 16;           // flat row b*N+n
  {
    const int r = tid >> 5;                 // 16 rows x 32 threads
    const int f0 = tid & 31;
    for (int f = f0; f < F_; f += 32)
      As[r * 136 + f] = A[(size_t)(m0 + r) * F_ + f];
  }
  __syncthreads();
  const float* Wg = W + (size_t)h * F_ * ND_;
  float acc[16];
#pragma unroll
  for (int r = 0; r < 16; ++r) acc[r] = 0.f;
  float w0 = Wg[0 * ND_ + lane], w1 = Wg[1 * ND_ + lane],
        w2 = Wg[2 * ND_ + lane], w3 = Wg[3 * ND_ + lane];
  int f = 0;
  for (; f + 7 < F_; f += 4) {
    const float n0 = Wg[(f + 4) * ND_ + lane];
    const float n1 = Wg[(f + 5) * ND_ + lane];
    const float n2 = Wg[(f + 6) * ND_ + lane];
    const float n3 = Wg[(f + 7) * ND_ + lane];
#pragma unroll
    for (int r = 0; r < 16; ++r) {
      float4 a = *reinterpret_cast<const float4*>(&As[r * 136 + f]);
      acc[r] = fmaf(a.x, w0, acc[r]);
      acc[r] = fmaf(a.y, w1, acc[r]);
      acc[r] = fmaf(a.z, w2, acc[r]);
      acc[r] = fmaf(a.w, w3, acc[r]);
    }
    w0 = n0; w1 = n1; w2 = n2; w3 = n3;
  }
  // last full 4-chunk (f = 128..131) with already-loaded w
#pragma unroll
  for (int r = 0; r < 16; ++r) {
    float4 a = *reinterpret_cast<const float4*>(&As[r * 136 + f]);
    acc[r] = fmaf(a.x, w0, acc[r]);
    acc[r] = fmaf(a.y, w1, acc[r]);
    acc[r] = fmaf(a.z, w2, acc[r]);
    acc[r] = fmaf(a.w, w3, acc[r]);
  }
  f += 4;
  for (; f < F_; ++f) {
    const float wv = Wg[f * ND_ + lane];
#pragma unroll
    for (int r = 0; r < 16; ++r)
      acc[r] = fmaf(As[r * 136 + f], wv, acc[r]);
  }
  float a1 = ah[h * 2 * ND_ + lane];
  float a2 = ah[h * 2 * ND_ + ND_ + lane];
  const int b = m0 >> 7, n0 = m0 & (N_ - 1);
  const size_t bh = (size_t)b * H_ + h;
#pragma unroll
  for (int r = 0; r < 16; ++r) {
    Wh[(bh * N_ + n0 + r) * ND_ + lane] = acc[r];
    float sv = wred_sum(acc[r] * a1);
    float dv = wred_sum(acc[r] * a2);
    if (lane == 0) {
      sb[bh * N_ + n0 + r] = sv;
      db[bh * N_ + n0 + r] = dv;
    }
  }
}

// K2: masked softmax over j + h = elu(attn @ Wh), written as hbuf[b,i,h*64+d].
__global__ __launch_bounds__(256) void k2_attn1(
    const float* __restrict__ Wh, const float* __restrict__ sb,
    const float* __restrict__ db, const int* __restrict__ adj,
    float* __restrict__ hb) {
  const int lane = threadIdx.x & 63;
  const int w = blockIdx.x * 4 + (threadIdx.x >> 6);  // 0..32767
  const int bh = w >> 4;
  const int i0 = (w & 15) * 8;
  const int b = bh >> 3, h = bh & 7;
  const float* dbase = db + (size_t)bh * N_;
  const float dv0 = dbase[lane], dv1 = dbase[64 + lane];
  float p0[8], p1[8];
#pragma unroll
  for (int r = 0; r < 8; ++r) {
    const int i = i0 + r;
    float sv = sb[(size_t)bh * N_ + i];
    const int* arow = adj + ((size_t)b * N_ + i) * N_;
    int a0 = arow[lane], a1i = arow[64 + lane];
    float e0 = a0 > 0 ? lrelu(sv + dv0) : NEG_;
    float e1 = a1i > 0 ? lrelu(sv + dv1) : NEG_;
    float mx = wred_max(fmaxf(e0, e1));
    float x0 = expf(e0 - mx), x1 = expf(e1 - mx);
    float inv = 1.f / wred_sum(x0 + x1);
    p0[r] = x0 * inv;
    p1[r] = x1 * inv;
  }
  const float* whb = Wh + (size_t)bh * N_ * ND_ + lane;
  float acc[8];
#pragma unroll
  for (int r = 0; r < 8; ++r) acc[r] = 0.f;
  for (int j = 0; j < 64; ++j) {
    float wv = whb[(size_t)j * ND_];
#pragma unroll
    for (int r = 0; r < 8; ++r) acc[r] = fmaf(rdlane(p0[r], j), wv, acc[r]);
  }
  for (int j = 0; j < 64; ++j) {
    float wv = whb[(size_t)(64 + j) * ND_];
#pragma unroll
    for (int r = 0; r < 8; ++r) acc[r] = fmaf(rdlane(p1[r], j), wv, acc[r]);
  }
  float* hrow = hb + ((size_t)b * N_ + i0) * (H_ * ND_) + h * ND_ + lane;
#pragma unroll
  for (int r = 0; r < 8; ++r) hrow[(size_t)r * (H_ * ND_)] = eluf(acc[r]);
}

// Tiled big-M GEMM, register-pressure-balanced:
// Block: 32 rows x 300 cols, 320 thr = 8 row-groups x 40 col-threads,
// thread tile 4 rows x 8 cols (acc 32 + A 16 + B 32 regs ~ fits 128, no spill).
// Grid M/32 = 1024 (4 blocks/CU). LDS 32xBK (8KB at BK=64).
// Per 4-k chunk: 4 ds_read_b128 (2 addrs/wave, free) + 8 B float4 + 128 FMA.
// k ascends per output element -> bitwise-stable vs previous rounds.
template <int K, int BK, int ACT, bool BATB>
__global__ __launch_bounds__(320, 4) void gemm_t(
    const float* __restrict__ A, const float* __restrict__ Bm,
    float* __restrict__ C) {
  __shared__ __align__(16) float As[32 * BK];
  const int tid = threadIdx.x;
  const int c = tid % 40;           // col-thread
  const int rg = tid / 40;          // row-group (0..7), 4 rows each
  const int m0 = blockIdx.x * 32;
  const int col0 = c * 8;
  const bool g0 = (col0 + 3) < HID_;
  const bool g1 = (col0 + 7) < HID_;
  const float* Bp = BATB ? Bm + (size_t)(m0 >> 7) * K * HID_ : Bm;
  float acc[4][8];
#pragma unroll
  for (int r = 0; r < 4; ++r)
#pragma unroll
    for (int j = 0; j < 8; ++j) acc[r][j] = 0.f;

  for (int k0 = 0; k0 < K; k0 += BK) {
    __syncthreads();
    for (int idx = tid * 4; idx < 32 * BK; idx += 320 * 4) {
      const int r = idx / BK, kk = idx % BK;
      *reinterpret_cast<float4*>(&As[idx]) =
          *reinterpret_cast<const float4*>(A + (size_t)(m0 + r) * K + k0 + kk);
    }
    __syncthreads();
#pragma unroll 2
    for (int k = 0; k < BK; k += 4) {
      float4 a4[4];
#pragma unroll
      for (int r = 0; r < 4; ++r)
        a4[r] = *reinterpret_cast<const float4*>(&As[(rg * 4 + r) * BK + k]);
      float4 b0[4], b1[4];
#pragma unroll
      for (int kk = 0; kk < 4; ++kk) {
        const float* brow = Bp + (size_t)(k0 + k + kk) * HID_ + col0;
        b0[kk] = g0 ? *reinterpret_cast<const float4*>(brow)
                    : float4{0.f, 0.f, 0.f, 0.f};
        b1[kk] = g1 ? *reinterpret_cast<const float4*>(brow + 4)
                    : float4{0.f, 0.f, 0.f, 0.f};
      }
#pragma unroll
      for (int kk = 0; kk < 4; ++kk) {
#pragma unroll
        for (int r = 0; r < 4; ++r) {
          const float av = (kk == 0)   ? a4[r].x
                           : (kk == 1) ? a4[r].y
                           : (kk == 2) ? a4[r].z
                                       : a4[r].w;
          acc[r][0] = fmaf(av, b0[kk].x, acc[r][0]);
          acc[r][1] = fmaf(av, b0[kk].y, acc[r][1]);
          acc[r][2] = fmaf(av, b0[kk].z, acc[r][2]);
          acc[r][3] = fmaf(av, b0[kk].w, acc[r][3]);
          acc[r][4] = fmaf(av, b1[kk].x, acc[r][4]);
          acc[r][5] = fmaf(av, b1[kk].y, acc[r][5]);
          acc[r][6] = fmaf(av, b1[kk].z, acc[r][6]);
          acc[r][7] = fmaf(av, b1[kk].w, acc[r][7]);
        }
      }
    }
  }
#pragma unroll
  for (int r = 0; r < 4; ++r) {
    float o[8];
#pragma unroll
    for (int j = 0; j < 8; ++j)
      o[j] = (ACT == 2) ? eluf(acc[r][j]) : acc[r][j];
    float* crow = C + (size_t)(m0 + rg * 4 + r) * HID_ + col0;
    if (g0) {
      float4 v = {o[0], o[1], o[2], o[3]};
      *reinterpret_cast<float4*>(crow) = v;
    }
    if (g1) {
      float4 v = {o[4], o[5], o[6], o[7]};
      *reinterpret_cast<float4*>(crow + 4) = v;
    }
  }
}

// Split-K partial GEMM for small-M matmuls: grid (M/ROWS, KSPLIT).
template <int ROWS, int KSPLIT>
__global__ void gemm_skp(const float* __restrict__ A, const float* __restrict__ Bm,
                         float* __restrict__ P, int M, int K, int N) {
  const int c = threadIdx.x;
  const int r0 = blockIdx.x * ROWS;
  const int ks = blockIdx.y;
  if (c >= N) return;
  const int kchunk = (K + KSPLIT - 1) / KSPLIT;
  const int k0 = ks * kchunk;
  const int k1 = (k0 + kchunk < K) ? (k0 + kchunk) : K;
  float acc[ROWS];
#pragma unroll
  for (int r = 0; r < ROWS; ++r) acc[r] = 0.f;
  int k = k0;
  for (; k + 3 < k1; k += 4) {
    const float b0 = Bm[(size_t)(k + 0) * N + c];
    const float b1 = Bm[(size_t)(k + 1) * N + c];
    const float b2 = Bm[(size_t)(k + 2) * N + c];
    const float b3 = Bm[(size_t)(k + 3) * N + c];
#pragma unroll
    for (int r = 0; r < ROWS; ++r) {
      float4 a = ld4u(A + (size_t)(r0 + r) * K + k);
      acc[r] = fmaf(a.x, b0, acc[r]);
      acc[r] = fmaf(a.y, b1, acc[r]);
      acc[r] = fmaf(a.z, b2, acc[r]);
      acc[r] = fmaf(a.w, b3, acc[r]);
    }
  }
  for (; k < k1; ++k) {
    const float bv = Bm[(size_t)k * N + c];
#pragma unroll
    for (int r = 0; r < ROWS; ++r)
      acc[r] = fmaf(A[(size_t)(r0 + r) * K + k], bv, acc[r]);
  }
#pragma unroll
  for (int r = 0; r < ROWS; ++r)
    P[((size_t)ks * M + r0 + r) * N + c] = acc[r];
}

// Reduce split-K partials + bias + act. act: 0 none, 1 relu.
template <int KSPLIT>
__global__ void k_red(const float* __restrict__ P, const float* __restrict__ bias,
                      float* __restrict__ C, int M, int N, int ldc, int act) {
  const int idx = blockIdx.x * 256 + threadIdx.x;
  if (idx >= M * N) return;
  const int m = idx / N, c = idx - m * N;
  float v = 0.f;
#pragma unroll
  for (int p = 0; p < KSPLIT; ++p) v += P[(size_t)p * M * N + idx];
  if (bias) v += bias[c];
  if (act == 1) v = fmaxf(v, 0.f);
  C[(size_t)m * ldc + c] = v;
}

// K4: s2/d2 = Wh2 @ a_out halves. One wave per row.
__global__ __launch_bounds__(256) void k4_sd2(
    const float* __restrict__ Wh2, const float* __restrict__ ao,
    float* __restrict__ s2, float* __restrict__ d2) {
  const int lane = threadIdx.x & 63;
  const int row = blockIdx.x * 4 + (threadIdx.x >> 6);
  const float* wrow = Wh2 + (size_t)row * HID_;
  float as = 0.f, ad = 0.f;
  for (int c = lane; c < HID_; c += 64) {
    float v = wrow[c];
    as = fmaf(v, ao[c], as);
    ad = fmaf(v, ao[HID_ + c], ad);
  }
  as = wred_sum(as);
  ad = wred_sum(ad);
  if (lane == 0) { s2[row] = as; d2[row] = ad; }
}

// K5: attn2 probabilities p2[b,i,j]. One wave per row i.
__global__ __launch_bounds__(256) void k5_p2(
    const float* __restrict__ s2, const float* __restrict__ d2,
    const int* __restrict__ adj, float* __restrict__ p2) {
  const int lane = threadIdx.x & 63;
  const int row = blockIdx.x * 4 + (threadIdx.x >> 6);  // b*N+i
  const int b = row >> 7;
  float sv = s2[row];
  const float* drow = d2 + (size_t)b * N_;
  const int* arow = adj + (size_t)row * N_;
  float dv0 = drow[lane], dv1 = drow[64 + lane];
  int a0 = arow[lane], a1i = arow[64 + lane];
  float e0 = a0 > 0 ? lrelu(sv + dv0) : NEG_;
  float e1 = a1i > 0 ? lrelu(sv + dv1) : NEG_;
  float mx = wred_max(fmaxf(e0, e1));
  float x0 = expf(e0 - mx), x1 = expf(e1 - mx);
  float inv = 1.f / wred_sum(x0 + x1);
  p2[(size_t)row * N_ + lane] = x0 * inv;
  p2[(size_t)row * N_ + 64 + lane] = x1 * inv;
}

// K7: per-row max and log-sum-exp over 300 cols. One wave per row.
__global__ __launch_bounds__(256) void k7_lse(
    const float* __restrict__ ob, float* __restrict__ mx, float* __restrict__ ls) {
  const int lane = threadIdx.x & 63;
  const int row = blockIdx.x * 4 + (threadIdx.x >> 6);
  const float* orow = ob + (size_t)row * HID_;
  float v[5], m = -1e30f;
#pragma unroll
  for (int q = 0; q < 5; ++q) {
    int c = lane + q * 64;
    v[q] = (c < HID_) ? orow[c] : -1e30f;
    m = fmaxf(m, v[q]);
  }
  m = wred_max(m);
  float s = 0.f;
#pragma unroll
  for (int q = 0; q < 5; ++q) {
    int c = lane + q * 64;
    if (c < HID_) s += expf(v[q] - m);
  }
  s = wred_sum(s);
  if (lane == 0) { mx[row] = m; ls[row] = logf(s); }
}

// K8: gat_out[b,c] = mean_i (ob[b,i,c] - mx - ls). grid 256, block 320.
__global__ void k8_mean(const float* __restrict__ ob, const float* __restrict__ mx,
                        const float* __restrict__ ls, float* __restrict__ gat) {
  const int c = threadIdx.x;
  const int b = blockIdx.x;
  if (c >= HID_) return;
  float acc = 0.f;
  for (int i = 0; i < N_; ++i) {
    int row = b * N_ + i;
    acc += ob[(size_t)row * HID_ + c] - mx[row] - ls[row];
  }
  gat[(size_t)b * HID_ + c] = acc * (1.f / N_);
}

// out[b] = sigmoid(y[b,:] @ ffn_w2 + b2). One wave per row.
__global__ __launch_bounds__(256) void k_final(
    const float* __restrict__ y, const float* __restrict__ w2,
    const float* __restrict__ b2, float* __restrict__ out) {
  const int lane = threadIdx.x & 63;
  const int b = blockIdx.x * 4 + (threadIdx.x >> 6);
  float acc = 0.f;
  for (int c = lane; c < HID_; c += 64)
    acc = fmaf(y[(size_t)b * HID_ + c], w2[c], acc);
  acc = wred_sum(acc);
  if (lane == 0) out[b] = 1.f / (1.f + expf(-(acc + b2[0])));
}

extern "C" void kernel_launch(void* const* d_in, const int* in_sizes, int n_in,
                              void* d_out, int out_size, void* d_ws, size_t ws_size,
                              hipStream_t stream) {
  const float* atom  = (const float*)d_in[0];
  const float* fp    = (const float*)d_in[1];
  const float* Whead = (const float*)d_in[2];
  const float* ah    = (const float*)d_in[3];
  const float* Wout  = (const float*)d_in[4];
  const float* aout  = (const float*)d_in[5];
  const float* fc1w  = (const float*)d_in[6];
  const float* fc1b  = (const float*)d_in[7];
  const float* fc2w  = (const float*)d_in[8];
  const float* fc2b  = (const float*)d_in[9];
  const float* fgw   = (const float*)d_in[10];
  const float* fgb   = (const float*)d_in[11];
  const float* ffw   = (const float*)d_in[12];
  const float* ffb   = (const float*)d_in[13];
  const float* w1    = (const float*)d_in[14];
  const float* b1    = (const float*)d_in[15];
  const float* w2    = (const float*)d_in[16];
  const float* b2    = (const float*)d_in[17];
  const int*   adj   = (const int*)d_in[18];
  float* out = (float*)d_out;

  float* ws = (float*)d_ws;
  // Aliased layout (peak ~139 MB of floats):
  float* Wh   = ws;                       // 16,777,216   [K1 w, K2 r]
  float* Wh2  = ws;                       //  9,830,400   [K3 w .. K6 r]  (Wh dead)
  float* pbuf = ws;                       // <=1,048,576  [split-K partials; only
                                          //  live before k1 and after k8]
  float* p2   = ws + 9830400;             //  4,194,304   [K5 w, K6 r]
  float* sb   = ws + 16777216;            //    262,144
  float* db   = ws + 17039360;            //    262,144
  float* hb   = ws + 17301504;            // 16,777,216   [K2 w, K3 r]
  float* ob   = ws + 17301504;            //  9,830,400   [K6 w ..]  (hb dead)
  float* s2   = ws + 34078720;
  float* d2   = s2 + 32768;
  float* mxb  = d2 + 32768;
  float* lsb  = mxb + 32768;
  float* gat  = lsb + 32768;              //  76,800
  float* fpn1 = gat + 76800;              // 131,072
  float* fpn2 = fpn1 + 131072;            //  76,800
  float* xcat = fpn2 + 76800;             // 153,600
  float* yb   = xcat + 153600;            //  76,800

  // FPN branch (before k1 so pbuf aliasing of Wh region is safe)
  gemm_skp<4, 8><<<dim3(64, 8), 512, 0, stream>>>(fp, fc1w, pbuf, B_, FPD_, FP2_);
  k_red<8><<<512, 256, 0, stream>>>(pbuf, fc1b, fpn1, B_, FP2_, FP2_, 1);
  gemm_skp<4, 4><<<dim3(64, 4), 320, 0, stream>>>(fpn1, fc2w, pbuf, B_, FP2_, HID_);
  k_red<4><<<300, 256, 0, stream>>>(pbuf, fc2b, fpn2, B_, HID_, HID_, 0);

  // GAT stage 1
  k1_wh<<<2048, 512, 0, stream>>>(atom, Whead, ah, Wh, sb, db);
  k2_attn1<<<8192, 256, 0, stream>>>(Wh, sb, db, adj, hb);

  // Wh2 = h @ W_out  (M=32768, K=512, N=300)
  gemm_t<512, 64, 0, false><<<1024, 320, 0, stream>>>(hb, Wout, Wh2);

  // GAT stage 2
  k4_sd2<<<8192, 256, 0, stream>>>(Wh2, aout, s2, d2);
  k5_p2<<<8192, 256, 0, stream>>>(s2, d2, adj, p2);
  // ob = elu(p2 @ Wh2)  (M=32768, K=128, N=300, B batched per 128 rows)
  gemm_t<128, 64, 2, true><<<1024, 320, 0, stream>>>(p2, Wh2, ob);
  k7_lse<<<8192, 256, 0, stream>>>(ob, mxb, lsb);
  k8_mean<<<256, 320, 0, stream>>>(ob, mxb, lsb, gat);

  // Head (after k8: entire low ws region dead -> pbuf reuse is safe)
  gemm_skp<4, 4><<<dim3(64, 4), 320, 0, stream>>>(gat, fgw, pbuf, B_, HID_, HID_);
  k_red<4><<<300, 256, 0, stream>>>(pbuf, fgb, xcat, B_, HID_, 2 * HID_, 1);
  gemm_skp<4, 4><<<dim3(64, 4), 320, 0, stream>>>(fpn2, ffw, pbuf, B_, HID_, HID_);
  k_red<4><<<300, 256, 0, stream>>>(pbuf, ffb, xcat + 300, B_, HID_, 2 * HID_, 1);
  gemm_skp<4, 4><<<dim3(64, 4), 320, 0, stream>>>(xcat, w1, pbuf, B_, 2 * HID_, HID_);
  k_red<4><<<300, 256, 0, stream>>>(pbuf, b1, yb, B_, HID_, HID_, 1);
  k_final<<<64, 256, 0, stream>>>(yb, w2, b2, out);
}

// Round 9
// 532.789 us; speedup vs baseline: 2.0365x; 2.0365x over previous
//
#include <hip/hip_runtime.h>
#include <math.h>

// Problem constants
#define B_    256
#define N_    128
#define F_    133
#define H_    8
#define ND_   64     // NHID
#define HID_  300
#define FPD_  1489
#define FP2_  512
#define ALPHA_ 0.2f
#define NEG_  -9.0e15f

typedef __bf16 bf16x8 __attribute__((ext_vector_type(8)));
typedef float f32x4 __attribute__((ext_vector_type(4)));

__device__ __forceinline__ float wred_sum(float v) {
#pragma unroll
  for (int m = 32; m >= 1; m >>= 1) v += __shfl_xor(v, m, 64);
  return v;
}
__device__ __forceinline__ float wred_max(float v) {
#pragma unroll
  for (int m = 32; m >= 1; m >>= 1) v = fmaxf(v, __shfl_xor(v, m, 64));
  return v;
}
__device__ __forceinline__ float lrelu(float x) { return x > 0.f ? x : ALPHA_ * x; }
__device__ __forceinline__ float eluf(float x)  { return x > 0.f ? x : expf(x) - 1.f; }
__device__ __forceinline__ float rdlane(float v, int l) {
  return __int_as_float(__builtin_amdgcn_readlane(__float_as_int(v), l));
}
// 16B load at 4B alignment (safe form)
__device__ __forceinline__ float4 ld4u(const float* p) {
  float4 v;
  __builtin_memcpy(&v, p, 16);
  return v;
}

// K1: Wh[b,h,n,d] = sum_f A[b,n,f] * W[h,f,d];  s/d projections fused.
// grid 2048, block 512 (8 waves; wave = head h, lane = d). 16 rows/block.
__global__ __launch_bounds__(512) void k1_wh(
    const float* __restrict__ A, const float* __restrict__ W,
    const float* __restrict__ ah, float* __restrict__ Wh,
    float* __restrict__ sb, float* __restrict__ db) {
  __shared__ __align__(16) float As[16 * 136];
  const int tid = threadIdx.x;
  const int lane = tid & 63;
  const int h = tid >> 6;
  const int m0 = blockIdx.x * 16;           // flat row b*N+n
  {
    const int r = tid >> 5;                 // 16 rows x 32 threads
    const int f0 = tid & 31;
    for (int f = f0; f < F_; f += 32)
      As[r * 136 + f] = A[(size_t)(m0 + r) * F_ + f];
  }
  __syncthreads();
  const float* Wg = W + (size_t)h * F_ * ND_;
  float acc[16];
#pragma unroll
  for (int r = 0; r < 16; ++r) acc[r] = 0.f;
  float w0 = Wg[0 * ND_ + lane], w1 = Wg[1 * ND_ + lane],
        w2 = Wg[2 * ND_ + lane], w3 = Wg[3 * ND_ + lane];
  int f = 0;
  for (; f + 7 < F_; f += 4) {
    const float n0 = Wg[(f + 4) * ND_ + lane];
    const float n1 = Wg[(f + 5) * ND_ + lane];
    const float n2 = Wg[(f + 6) * ND_ + lane];
    const float n3 = Wg[(f + 7) * ND_ + lane];
#pragma unroll
    for (int r = 0; r < 16; ++r) {
      float4 a = *reinterpret_cast<const float4*>(&As[r * 136 + f]);
      acc[r] = fmaf(a.x, w0, acc[r]);
      acc[r] = fmaf(a.y, w1, acc[r]);
      acc[r] = fmaf(a.z, w2, acc[r]);
      acc[r] = fmaf(a.w, w3, acc[r]);
    }
    w0 = n0; w1 = n1; w2 = n2; w3 = n3;
  }
  // last full 4-chunk (f = 128..131) with already-loaded w
#pragma unroll
  for (int r = 0; r < 16; ++r) {
    float4 a = *reinterpret_cast<const float4*>(&As[r * 136 + f]);
    acc[r] = fmaf(a.x, w0, acc[r]);
    acc[r] = fmaf(a.y, w1, acc[r]);
    acc[r] = fmaf(a.z, w2, acc[r]);
    acc[r] = fmaf(a.w, w3, acc[r]);
  }
  f += 4;
  for (; f < F_; ++f) {
    const float wv = Wg[f * ND_ + lane];
#pragma unroll
    for (int r = 0; r < 16; ++r)
      acc[r] = fmaf(As[r * 136 + f], wv, acc[r]);
  }
  float a1 = ah[h * 2 * ND_ + lane];
  float a2 = ah[h * 2 * ND_ + ND_ + lane];
  const int b = m0 >> 7, n0 = m0 & (N_ - 1);
  const size_t bh = (size_t)b * H_ + h;
#pragma unroll
  for (int r = 0; r < 16; ++r) {
    Wh[(bh * N_ + n0 + r) * ND_ + lane] = acc[r];
    float sv = wred_sum(acc[r] * a1);
    float dv = wred_sum(acc[r] * a2);
    if (lane == 0) {
      sb[bh * N_ + n0 + r] = sv;
      db[bh * N_ + n0 + r] = dv;
    }
  }
}

// K2: masked softmax over j + h = elu(attn @ Wh), written as hbuf[b,i,h*64+d].
__global__ __launch_bounds__(256) void k2_attn1(
    const float* __restrict__ Wh, const float* __restrict__ sb,
    const float* __restrict__ db, const int* __restrict__ adj,
    float* __restrict__ hb) {
  const int lane = threadIdx.x & 63;
  const int w = blockIdx.x * 4 + (threadIdx.x >> 6);  // 0..32767
  const int bh = w >> 4;
  const int i0 = (w & 15) * 8;
  const int b = bh >> 3, h = bh & 7;
  const float* dbase = db + (size_t)bh * N_;
  const float dv0 = dbase[lane], dv1 = dbase[64 + lane];
  float p0[8], p1[8];
#pragma unroll
  for (int r = 0; r < 8; ++r) {
    const int i = i0 + r;
    float sv = sb[(size_t)bh * N_ + i];
    const int* arow = adj + ((size_t)b * N_ + i) * N_;
    int a0 = arow[lane], a1i = arow[64 + lane];
    float e0 = a0 > 0 ? lrelu(sv + dv0) : NEG_;
    float e1 = a1i > 0 ? lrelu(sv + dv1) : NEG_;
    float mx = wred_max(fmaxf(e0, e1));
    float x0 = expf(e0 - mx), x1 = expf(e1 - mx);
    float inv = 1.f / wred_sum(x0 + x1);
    p0[r] = x0 * inv;
    p1[r] = x1 * inv;
  }
  const float* whb = Wh + (size_t)bh * N_ * ND_ + lane;
  float acc[8];
#pragma unroll
  for (int r = 0; r < 8; ++r) acc[r] = 0.f;
  for (int j = 0; j < 64; ++j) {
    float wv = whb[(size_t)j * ND_];
#pragma unroll
    for (int r = 0; r < 8; ++r) acc[r] = fmaf(rdlane(p0[r], j), wv, acc[r]);
  }
  for (int j = 0; j < 64; ++j) {
    float wv = whb[(size_t)(64 + j) * ND_];
#pragma unroll
    for (int r = 0; r < 8; ++r) acc[r] = fmaf(rdlane(p1[r], j), wv, acc[r]);
  }
  float* hrow = hb + ((size_t)b * N_ + i0) * (H_ * ND_) + h * ND_ + lane;
#pragma unroll
  for (int r = 0; r < 8; ++r) hrow[(size_t)r * (H_ * ND_)] = eluf(acc[r]);
}

// MFMA split-bf16 GEMM: C = act(A @ B), A MxK fp32 (K%32==0), B KxN fp32,
// N=300. D ~= Al*Bh + Ah*Bl + Ah*Bh accumulated fp32 (error ~1e-4 rel).
// Wave = 16 rows x colhalf (10 or 9 tiles of 16x16). Block 256 thr = 4 waves
// (2 row-strips x 2 colhalves), BM=32, grid M/32=1024. No LDS.
// Fragment layouts per cdna4 guide (C/D verified m89): A row=lane&15,
// k=(lane>>4)*8+j; B col=lane&15, same k; D col=lane&15, row=(lane>>4)*4+reg.
template <int K, int ACT, bool BATB>
__global__ __launch_bounds__(256) void gemm_mfma(
    const float* __restrict__ A, const float* __restrict__ Bm,
    float* __restrict__ C) {
  const int tid = threadIdx.x;
  const int lane = tid & 63;
  const int wv = tid >> 6;
  const int rs = wv >> 1;           // row-strip in block
  const int ch = wv & 1;            // col-half
  const int m0 = blockIdx.x * 32 + rs * 16;
  const float* Ap = A + (size_t)(m0 + (lane & 15)) * K + ((lane >> 4) * 8);
  const float* Bp = BATB ? Bm + (size_t)(m0 >> 7) * K * HID_ : Bm;
  const int ct0 = ch * 10;
  const int nct = ch ? 9 : 10;      // tiles 0..9 / 10..18 (col 160..299)
  f32x4 acc[10];
#pragma unroll
  for (int t = 0; t < 10; ++t) acc[t] = f32x4{0.f, 0.f, 0.f, 0.f};

  for (int ks = 0; ks < K / 32; ++ks) {
    float4 a0 = *reinterpret_cast<const float4*>(Ap + ks * 32);
    float4 a1 = *reinterpret_cast<const float4*>(Ap + ks * 32 + 4);
    float av[8] = {a0.x, a0.y, a0.z, a0.w, a1.x, a1.y, a1.z, a1.w};
    bf16x8 ah, al;
#pragma unroll
    for (int j = 0; j < 8; ++j) {
      float v = av[j];
      __bf16 hv = (__bf16)v;
      ah[j] = hv;
      al[j] = (__bf16)(v - (float)hv);
    }
    const int kb = ks * 32 + (lane >> 4) * 8;
#pragma unroll
    for (int t = 0; t < 10; ++t) {
      if (t < nct) {
        const int col = (ct0 + t) * 16 + (lane & 15);
        const bool cv = col < HID_;
        const float* Bc = Bp + (size_t)kb * HID_ + col;
        float bv[8];
#pragma unroll
        for (int i = 0; i < 8; ++i) bv[i] = cv ? Bc[(size_t)i * HID_] : 0.f;
        bf16x8 bh, bl;
#pragma unroll
        for (int j = 0; j < 8; ++j) {
          float v = bv[j];
          __bf16 hv = (__bf16)v;
          bh[j] = hv;
          bl[j] = (__bf16)(v - (float)hv);
        }
        acc[t] = __builtin_amdgcn_mfma_f32_16x16x32_bf16(al, bh, acc[t], 0, 0, 0);
        acc[t] = __builtin_amdgcn_mfma_f32_16x16x32_bf16(ah, bl, acc[t], 0, 0, 0);
        acc[t] = __builtin_amdgcn_mfma_f32_16x16x32_bf16(ah, bh, acc[t], 0, 0, 0);
      }
    }
  }

  const int orow = m0 + (lane >> 4) * 4;
  const int ocol0 = (lane & 15);
#pragma unroll
  for (int t = 0; t < 10; ++t) {
    if (t < nct) {
      const int col = (ct0 + t) * 16 + ocol0;
      if (col < HID_) {
#pragma unroll
        for (int r = 0; r < 4; ++r) {
          float v = acc[t][r];
          if (ACT == 2) v = eluf(v);
          C[(size_t)(orow + r) * HID_ + col] = v;
        }
      }
    }
  }
}

// Split-K partial GEMM for small-M matmuls: grid (M/ROWS, KSPLIT).
template <int ROWS, int KSPLIT>
__global__ void gemm_skp(const float* __restrict__ A, const float* __restrict__ Bm,
                         float* __restrict__ P, int M, int K, int N) {
  const int c = threadIdx.x;
  const int r0 = blockIdx.x * ROWS;
  const int ks = blockIdx.y;
  if (c >= N) return;
  const int kchunk = (K + KSPLIT - 1) / KSPLIT;
  const int k0 = ks * kchunk;
  const int k1 = (k0 + kchunk < K) ? (k0 + kchunk) : K;
  float acc[ROWS];
#pragma unroll
  for (int r = 0; r < ROWS; ++r) acc[r] = 0.f;
  int k = k0;
  for (; k + 3 < k1; k += 4) {
    const float b0 = Bm[(size_t)(k + 0) * N + c];
    const float b1 = Bm[(size_t)(k + 1) * N + c];
    const float b2 = Bm[(size_t)(k + 2) * N + c];
    const float b3 = Bm[(size_t)(k + 3) * N + c];
#pragma unroll
    for (int r = 0; r < ROWS; ++r) {
      float4 a = ld4u(A + (size_t)(r0 + r) * K + k);
      acc[r] = fmaf(a.x, b0, acc[r]);
      acc[r] = fmaf(a.y, b1, acc[r]);
      acc[r] = fmaf(a.z, b2, acc[r]);
      acc[r] = fmaf(a.w, b3, acc[r]);
    }
  }
  for (; k < k1; ++k) {
    const float bv = Bm[(size_t)k * N + c];
#pragma unroll
    for (int r = 0; r < ROWS; ++r)
      acc[r] = fmaf(A[(size_t)(r0 + r) * K + k], bv, acc[r]);
  }
#pragma unroll
  for (int r = 0; r < ROWS; ++r)
    P[((size_t)ks * M + r0 + r) * N + c] = acc[r];
}

// Reduce split-K partials + bias + act. act: 0 none, 1 relu.
template <int KSPLIT>
__global__ void k_red(const float* __restrict__ P, const float* __restrict__ bias,
                      float* __restrict__ C, int M, int N, int ldc, int act) {
  const int idx = blockIdx.x * 256 + threadIdx.x;
  if (idx >= M * N) return;
  const int m = idx / N, c = idx - m * N;
  float v = 0.f;
#pragma unroll
  for (int p = 0; p < KSPLIT; ++p) v += P[(size_t)p * M * N + idx];
  if (bias) v += bias[c];
  if (act == 1) v = fmaxf(v, 0.f);
  C[(size_t)m * ldc + c] = v;
}

// K4: s2/d2 = Wh2 @ a_out halves. One wave per row.
__global__ __launch_bounds__(256) void k4_sd2(
    const float* __restrict__ Wh2, const float* __restrict__ ao,
    float* __restrict__ s2, float* __restrict__ d2) {
  const int lane = threadIdx.x & 63;
  const int row = blockIdx.x * 4 + (threadIdx.x >> 6);
  const float* wrow = Wh2 + (size_t)row * HID_;
  float as = 0.f, ad = 0.f;
  for (int c = lane; c < HID_; c += 64) {
    float v = wrow[c];
    as = fmaf(v, ao[c], as);
    ad = fmaf(v, ao[HID_ + c], ad);
  }
  as = wred_sum(as);
  ad = wred_sum(ad);
  if (lane == 0) { s2[row] = as; d2[row] = ad; }
}

// K5: attn2 probabilities p2[b,i,j]. One wave per row i.
__global__ __launch_bounds__(256) void k5_p2(
    const float* __restrict__ s2, const float* __restrict__ d2,
    const int* __restrict__ adj, float* __restrict__ p2) {
  const int lane = threadIdx.x & 63;
  const int row = blockIdx.x * 4 + (threadIdx.x >> 6);  // b*N+i
  const int b = row >> 7;
  float sv = s2[row];
  const float* drow = d2 + (size_t)b * N_;
  const int* arow = adj + (size_t)row * N_;
  float dv0 = drow[lane], dv1 = drow[64 + lane];
  int a0 = arow[lane], a1i = arow[64 + lane];
  float e0 = a0 > 0 ? lrelu(sv + dv0) : NEG_;
  float e1 = a1i > 0 ? lrelu(sv + dv1) : NEG_;
  float mx = wred_max(fmaxf(e0, e1));
  float x0 = expf(e0 - mx), x1 = expf(e1 - mx);
  float inv = 1.f / wred_sum(x0 + x1);
  p2[(size_t)row * N_ + lane] = x0 * inv;
  p2[(size_t)row * N_ + 64 + lane] = x1 * inv;
}

// K7: per-row max and log-sum-exp over 300 cols. One wave per row.
__global__ __launch_bounds__(256) void k7_lse(
    const float* __restrict__ ob, float* __restrict__ mx, float* __restrict__ ls) {
  const int lane = threadIdx.x & 63;
  const int row = blockIdx.x * 4 + (threadIdx.x >> 6);
  const float* orow = ob + (size_t)row * HID_;
  float v[5], m = -1e30f;
#pragma unroll
  for (int q = 0; q < 5; ++q) {
    int c = lane + q * 64;
    v[q] = (c < HID_) ? orow[c] : -1e30f;
    m = fmaxf(m, v[q]);
  }
  m = wred_max(m);
  float s = 0.f;
#pragma unroll
  for (int q = 0; q < 5; ++q) {
    int c = lane + q * 64;
    if (c < HID_) s += expf(v[q] - m);
  }
  s = wred_sum(s);
  if (lane == 0) { mx[row] = m; ls[row] = logf(s); }
}

// K8: gat_out[b,c] = mean_i (ob[b,i,c] - mx - ls). grid 256, block 320.
__global__ void k8_mean(const float* __restrict__ ob, const float* __restrict__ mx,
                        const float* __restrict__ ls, float* __restrict__ gat) {
  const int c = threadIdx.x;
  const int b = blockIdx.x;
  if (c >= HID_) return;
  float acc = 0.f;
  for (int i = 0; i < N_; ++i) {
    int row = b * N_ + i;
    acc += ob[(size_t)row * HID_ + c] - mx[row] - ls[row];
  }
  gat[(size_t)b * HID_ + c] = acc * (1.f / N_);
}

// out[b] = sigmoid(y[b,:] @ ffn_w2 + b2). One wave per row.
__global__ __launch_bounds__(256) void k_final(
    const float* __restrict__ y, const float* __restrict__ w2,
    const float* __restrict__ b2, float* __restrict__ out) {
  const int lane = threadIdx.x & 63;
  const int b = blockIdx.x * 4 + (threadIdx.x >> 6);
  float acc = 0.f;
  for (int c = lane; c < HID_; c += 64)
    acc = fmaf(y[(size_t)b * HID_ + c], w2[c], acc);
  acc = wred_sum(acc);
  if (lane == 0) out[b] = 1.f / (1.f + expf(-(acc + b2[0])));
}

extern "C" void kernel_launch(void* const* d_in, const int* in_sizes, int n_in,
                              void* d_out, int out_size, void* d_ws, size_t ws_size,
                              hipStream_t stream) {
  const float* atom  = (const float*)d_in[0];
  const float* fp    = (const float*)d_in[1];
  const float* Whead = (const float*)d_in[2];
  const float* ah    = (const float*)d_in[3];
  const float* Wout  = (const float*)d_in[4];
  const float* aout  = (const float*)d_in[5];
  const float* fc1w  = (const float*)d_in[6];
  const float* fc1b  = (const float*)d_in[7];
  const float* fc2w  = (const float*)d_in[8];
  const float* fc2b  = (const float*)d_in[9];
  const float* fgw   = (const float*)d_in[10];
  const float* fgb   = (const float*)d_in[11];
  const float* ffw   = (const float*)d_in[12];
  const float* ffb   = (const float*)d_in[13];
  const float* w1    = (const float*)d_in[14];
  const float* b1    = (const float*)d_in[15];
  const float* w2    = (const float*)d_in[16];
  const float* b2    = (const float*)d_in[17];
  const int*   adj   = (const int*)d_in[18];
  float* out = (float*)d_out;

  float* ws = (float*)d_ws;
  // Aliased layout (peak ~139 MB of floats):
  float* Wh   = ws;                       // 16,777,216   [K1 w, K2 r]
  float* Wh2  = ws;                       //  9,830,400   [K3 w .. K6 r]  (Wh dead)
  float* pbuf = ws;                       // <=1,048,576  [split-K partials; only
                                          //  live before k1 and after k8]
  float* p2   = ws + 9830400;             //  4,194,304   [K5 w, K6 r]
  float* sb   = ws + 16777216;            //    262,144
  float* db   = ws + 17039360;            //    262,144
  float* hb   = ws + 17301504;            // 16,777,216   [K2 w, K3 r]
  float* ob   = ws + 17301504;            //  9,830,400   [K6 w ..]  (hb dead)
  float* s2   = ws + 34078720;
  float* d2   = s2 + 32768;
  float* mxb  = d2 + 32768;
  float* lsb  = mxb + 32768;
  float* gat  = lsb + 32768;              //  76,800
  float* fpn1 = gat + 76800;              // 131,072
  float* fpn2 = fpn1 + 131072;            //  76,800
  float* xcat = fpn2 + 76800;             // 153,600
  float* yb   = xcat + 153600;            //  76,800

  // FPN branch (before k1 so pbuf aliasing of Wh region is safe)
  gemm_skp<4, 8><<<dim3(64, 8), 512, 0, stream>>>(fp, fc1w, pbuf, B_, FPD_, FP2_);
  k_red<8><<<512, 256, 0, stream>>>(pbuf, fc1b, fpn1, B_, FP2_, FP2_, 1);
  gemm_skp<4, 4><<<dim3(64, 4), 320, 0, stream>>>(fpn1, fc2w, pbuf, B_, FP2_, HID_);
  k_red<4><<<300, 256, 0, stream>>>(pbuf, fc2b, fpn2, B_, HID_, HID_, 0);

  // GAT stage 1
  k1_wh<<<2048, 512, 0, stream>>>(atom, Whead, ah, Wh, sb, db);
  k2_attn1<<<8192, 256, 0, stream>>>(Wh, sb, db, adj, hb);

  // Wh2 = h @ W_out  (M=32768, K=512, N=300) — MFMA split-bf16
  gemm_mfma<512, 0, false><<<1024, 256, 0, stream>>>(hb, Wout, Wh2);

  // GAT stage 2
  k4_sd2<<<8192, 256, 0, stream>>>(Wh2, aout, s2, d2);
  k5_p2<<<8192, 256, 0, stream>>>(s2, d2, adj, p2);
  // ob = elu(p2 @ Wh2)  (M=32768, K=128, N=300, B batched per 128 rows)
  gemm_mfma<128, 2, true><<<1024, 256, 0, stream>>>(p2, Wh2, ob);
  k7_lse<<<8192, 256, 0, stream>>>(ob, mxb, lsb);
  k8_mean<<<256, 320, 0, stream>>>(ob, mxb, lsb, gat);

  // Head (after k8: entire low ws region dead -> pbuf reuse is safe)
  gemm_skp<4, 4><<<dim3(64, 4), 320, 0, stream>>>(gat, fgw, pbuf, B_, HID_, HID_);
  k_red<4><<<300, 256, 0, stream>>>(pbuf, fgb, xcat, B_, HID_, 2 * HID_, 1);
  gemm_skp<4, 4><<<dim3(64, 4), 320, 0, stream>>>(fpn2, ffw, pbuf, B_, HID_, HID_);
  k_red<4><<<300, 256, 0, stream>>>(pbuf, ffb, xcat + 300, B_, HID_, 2 * HID_, 1);
  gemm_skp<4, 4><<<dim3(64, 4), 320, 0, stream>>>(xcat, w1, pbuf, B_, 2 * HID_, HID_);
  k_red<4><<<300, 256, 0, stream>>>(pbuf, b1, yb, B_, HID_, HID_, 1);
  k_final<<<64, 256, 0, stream>>>(yb, w2, b2, out);
}

// Round 10
// 458.448 us; speedup vs baseline: 2.3667x; 1.1622x over previous
//
#include <hip/hip_runtime.h>
#include <math.h>

// Problem constants
#define B_    256
#define N_    128
#define F_    133
#define H_    8
#define ND_   64     // NHID
#define HID_  300
#define FPD_  1489
#define FP2_  512
#define ALPHA_ 0.2f
#define NEG_  -9.0e15f

typedef __bf16 bf16x8 __attribute__((ext_vector_type(8)));
typedef float f32x4 __attribute__((ext_vector_type(4)));

__device__ __forceinline__ float wred_sum(float v) {
#pragma unroll
  for (int m = 32; m >= 1; m >>= 1) v += __shfl_xor(v, m, 64);
  return v;
}
__device__ __forceinline__ float wred_max(float v) {
#pragma unroll
  for (int m = 32; m >= 1; m >>= 1) v = fmaxf(v, __shfl_xor(v, m, 64));
  return v;
}
__device__ __forceinline__ float lrelu(float x) { return x > 0.f ? x : ALPHA_ * x; }
__device__ __forceinline__ float eluf(float x)  { return x > 0.f ? x : expf(x) - 1.f; }
// 16B load at 4B alignment (safe form)
__device__ __forceinline__ float4 ld4u(const float* p) {
  float4 v;
  __builtin_memcpy(&v, p, 16);
  return v;
}

// K1: Wh[b,h,n,d] = sum_f A[b,n,f] * W[h,f,d];  s/d projections fused.
// grid 2048, block 512 (8 waves; wave = head h, lane = d). 16 rows/block.
__global__ __launch_bounds__(512) void k1_wh(
    const float* __restrict__ A, const float* __restrict__ W,
    const float* __restrict__ ah, float* __restrict__ Wh,
    float* __restrict__ sb, float* __restrict__ db) {
  __shared__ __align__(16) float As[16 * 136];
  const int tid = threadIdx.x;
  const int lane = tid & 63;
  const int h = tid >> 6;
  const int m0 = blockIdx.x * 16;           // flat row b*N+n
  {
    const int r = tid >> 5;                 // 16 rows x 32 threads
    const int f0 = tid & 31;
    for (int f = f0; f < F_; f += 32)
      As[r * 136 + f] = A[(size_t)(m0 + r) * F_ + f];
  }
  __syncthreads();
  const float* Wg = W + (size_t)h * F_ * ND_;
  float acc[16];
#pragma unroll
  for (int r = 0; r < 16; ++r) acc[r] = 0.f;
  float w0 = Wg[0 * ND_ + lane], w1 = Wg[1 * ND_ + lane],
        w2 = Wg[2 * ND_ + lane], w3 = Wg[3 * ND_ + lane];
  int f = 0;
  for (; f + 7 < F_; f += 4) {
    const float n0 = Wg[(f + 4) * ND_ + lane];
    const float n1 = Wg[(f + 5) * ND_ + lane];
    const float n2 = Wg[(f + 6) * ND_ + lane];
    const float n3 = Wg[(f + 7) * ND_ + lane];
#pragma unroll
    for (int r = 0; r < 16; ++r) {
      float4 a = *reinterpret_cast<const float4*>(&As[r * 136 + f]);
      acc[r] = fmaf(a.x, w0, acc[r]);
      acc[r] = fmaf(a.y, w1, acc[r]);
      acc[r] = fmaf(a.z, w2, acc[r]);
      acc[r] = fmaf(a.w, w3, acc[r]);
    }
    w0 = n0; w1 = n1; w2 = n2; w3 = n3;
  }
  // last full 4-chunk (f = 128..131) with already-loaded w
#pragma unroll
  for (int r = 0; r < 16; ++r) {
    float4 a = *reinterpret_cast<const float4*>(&As[r * 136 + f]);
    acc[r] = fmaf(a.x, w0, acc[r]);
    acc[r] = fmaf(a.y, w1, acc[r]);
    acc[r] = fmaf(a.z, w2, acc[r]);
    acc[r] = fmaf(a.w, w3, acc[r]);
  }
  f += 4;
  for (; f < F_; ++f) {
    const float wv = Wg[f * ND_ + lane];
#pragma unroll
    for (int r = 0; r < 16; ++r)
      acc[r] = fmaf(As[r * 136 + f], wv, acc[r]);
  }
  float a1 = ah[h * 2 * ND_ + lane];
  float a2 = ah[h * 2 * ND_ + ND_ + lane];
  const int b = m0 >> 7, n0 = m0 & (N_ - 1);
  const size_t bh = (size_t)b * H_ + h;
#pragma unroll
  for (int r = 0; r < 16; ++r) {
    Wh[(bh * N_ + n0 + r) * ND_ + lane] = acc[r];
    float sv = wred_sum(acc[r] * a1);
    float dv = wred_sum(acc[r] * a2);
    if (lane == 0) {
      sb[bh * N_ + n0 + r] = sv;
      db[bh * N_ + n0 + r] = dv;
    }
  }
}

// K2: masked softmax + h = elu(attn @ Wh) via MFMA.
// One block = one (b,h) panel. 512 thr / 8 waves. LDS: p split-bf16
// [128][136] + Wh^T split-bf16 [64][136] (pad 136 -> 16B-aligned b128 reads).
// Phase 1: wave-parallel softmax (16 rows/wave), adj loads batch-issued.
// Phase 2: wave = 16-row strip; 4 col-tiles x 4 k-steps x 3 MFMA
// (split-bf16: Al*Bh + Ah*Bl + Ah*Bh, same convention as gemm_mfma).
__global__ __launch_bounds__(512) void k2_attn1(
    const float* __restrict__ Wh, const float* __restrict__ sb,
    const float* __restrict__ db, const int* __restrict__ adj,
    float* __restrict__ hb) {
  __shared__ __align__(16) __bf16 ph[128 * 136];
  __shared__ __align__(16) __bf16 pl[128 * 136];
  __shared__ __align__(16) __bf16 wth[64 * 136];
  __shared__ __align__(16) __bf16 wtl[64 * 136];
  const int tid = threadIdx.x;
  const int lane = tid & 63;
  const int w = tid >> 6;           // wave 0..7
  const int bh = blockIdx.x;
  const int b = bh >> 3, h = bh & 7;

  // Phase 0: stage Wh panel transposed + split-bf16.
  {
    const float* Whp = Wh + (size_t)bh * N_ * ND_;
    for (int idx = tid; idx < N_ * ND_; idx += 512) {
      const int j = idx >> 6, d = idx & 63;
      float v = Whp[idx];
      __bf16 hv = (__bf16)v;
      wth[d * 136 + j] = hv;
      wtl[d * 136 + j] = (__bf16)(v - (float)hv);
    }
  }

  // Phase 1: masked softmax for rows w*16 .. w*16+15.
  {
    const float dv0 = db[(size_t)bh * N_ + lane];
    const float dv1 = db[(size_t)bh * N_ + 64 + lane];
    const int i0 = w * 16;
    int a0v[16], a1v[16];
#pragma unroll
    for (int r = 0; r < 16; ++r) {
      const int* arow = adj + ((size_t)b * N_ + i0 + r) * N_;
      a0v[r] = arow[lane];
      a1v[r] = arow[64 + lane];
    }
#pragma unroll
    for (int r = 0; r < 16; ++r) {
      const int i = i0 + r;
      const float sv = sb[(size_t)bh * N_ + i];
      float e0 = a0v[r] > 0 ? lrelu(sv + dv0) : NEG_;
      float e1 = a1v[r] > 0 ? lrelu(sv + dv1) : NEG_;
      float mx = wred_max(fmaxf(e0, e1));
      float x0 = expf(e0 - mx), x1 = expf(e1 - mx);
      float inv = 1.f / wred_sum(x0 + x1);
      float p0 = x0 * inv, p1 = x1 * inv;
      __bf16 h0 = (__bf16)p0, h1 = (__bf16)p1;
      ph[i * 136 + lane] = h0;
      ph[i * 136 + 64 + lane] = h1;
      pl[i * 136 + lane] = (__bf16)(p0 - (float)h0);
      pl[i * 136 + 64 + lane] = (__bf16)(p1 - (float)h1);
    }
  }
  __syncthreads();

  // Phase 2: strip rows m0..m0+15 = p_strip(16x128) @ Wh(128x64), MFMA.
  {
    const int m0 = w * 16;
    const int arow = m0 + (lane & 15);
    f32x4 acc[4];
#pragma unroll
    for (int t = 0; t < 4; ++t) acc[t] = f32x4{0.f, 0.f, 0.f, 0.f};
#pragma unroll
    for (int ks = 0; ks < 4; ++ks) {
      const int kb = ks * 32 + (lane >> 4) * 8;
      bf16x8 ah8 = *reinterpret_cast<const bf16x8*>(&ph[arow * 136 + kb]);
      bf16x8 al8 = *reinterpret_cast<const bf16x8*>(&pl[arow * 136 + kb]);
#pragma unroll
      for (int ct = 0; ct < 4; ++ct) {
        const int col = ct * 16 + (lane & 15);
        bf16x8 bh8 = *reinterpret_cast<const bf16x8*>(&wth[col * 136 + kb]);
        bf16x8 bl8 = *reinterpret_cast<const bf16x8*>(&wtl[col * 136 + kb]);
        acc[ct] = __builtin_amdgcn_mfma_f32_16x16x32_bf16(al8, bh8, acc[ct], 0, 0, 0);
        acc[ct] = __builtin_amdgcn_mfma_f32_16x16x32_bf16(ah8, bl8, acc[ct], 0, 0, 0);
        acc[ct] = __builtin_amdgcn_mfma_f32_16x16x32_bf16(ah8, bh8, acc[ct], 0, 0, 0);
      }
    }
    const int orow0 = m0 + (lane >> 4) * 4;
#pragma unroll
    for (int ct = 0; ct < 4; ++ct) {
      const int d = ct * 16 + (lane & 15);
#pragma unroll
      for (int r = 0; r < 4; ++r) {
        const int i = orow0 + r;
        hb[((size_t)b * N_ + i) * (H_ * ND_) + h * ND_ + d] = eluf(acc[ct][r]);
      }
    }
  }
}

// MFMA split-bf16 GEMM: C = act(A @ B), A MxK fp32 (K%32==0), B KxN fp32,
// N=300. D ~= Al*Bh + Ah*Bl + Ah*Bh accumulated fp32.
// Wave = 16 rows x colhalf (10 or 9 tiles of 16x16). Block 256 thr = 4 waves
// (2 row-strips x 2 colhalves), BM=32, grid M/32=1024. No LDS.
template <int K, int ACT, bool BATB>
__global__ __launch_bounds__(256) void gemm_mfma(
    const float* __restrict__ A, const float* __restrict__ Bm,
    float* __restrict__ C) {
  const int tid = threadIdx.x;
  const int lane = tid & 63;
  const int wv = tid >> 6;
  const int rs = wv >> 1;           // row-strip in block
  const int ch = wv & 1;            // col-half
  const int m0 = blockIdx.x * 32 + rs * 16;
  const float* Ap = A + (size_t)(m0 + (lane & 15)) * K + ((lane >> 4) * 8);
  const float* Bp = BATB ? Bm + (size_t)(m0 >> 7) * K * HID_ : Bm;
  const int ct0 = ch * 10;
  const int nct = ch ? 9 : 10;      // tiles 0..9 / 10..18 (col 160..299)
  f32x4 acc[10];
#pragma unroll
  for (int t = 0; t < 10; ++t) acc[t] = f32x4{0.f, 0.f, 0.f, 0.f};

  for (int ks = 0; ks < K / 32; ++ks) {
    float4 a0 = *reinterpret_cast<const float4*>(Ap + ks * 32);
    float4 a1 = *reinterpret_cast<const float4*>(Ap + ks * 32 + 4);
    float av[8] = {a0.x, a0.y, a0.z, a0.w, a1.x, a1.y, a1.z, a1.w};
    bf16x8 ah, al;
#pragma unroll
    for (int j = 0; j < 8; ++j) {
      float v = av[j];
      __bf16 hv = (__bf16)v;
      ah[j] = hv;
      al[j] = (__bf16)(v - (float)hv);
    }
    const int kb = ks * 32 + (lane >> 4) * 8;
#pragma unroll
    for (int t = 0; t < 10; ++t) {
      if (t < nct) {
        const int col = (ct0 + t) * 16 + (lane & 15);
        const bool cv = col < HID_;
        const float* Bc = Bp + (size_t)kb * HID_ + col;
        float bv[8];
#pragma unroll
        for (int i = 0; i < 8; ++i) bv[i] = cv ? Bc[(size_t)i * HID_] : 0.f;
        bf16x8 bh, bl;
#pragma unroll
        for (int j = 0; j < 8; ++j) {
          float v = bv[j];
          __bf16 hv = (__bf16)v;
          bh[j] = hv;
          bl[j] = (__bf16)(v - (float)hv);
        }
        acc[t] = __builtin_amdgcn_mfma_f32_16x16x32_bf16(al, bh, acc[t], 0, 0, 0);
        acc[t] = __builtin_amdgcn_mfma_f32_16x16x32_bf16(ah, bl, acc[t], 0, 0, 0);
        acc[t] = __builtin_amdgcn_mfma_f32_16x16x32_bf16(ah, bh, acc[t], 0, 0, 0);
      }
    }
  }

  const int orow = m0 + (lane >> 4) * 4;
  const int ocol0 = (lane & 15);
#pragma unroll
  for (int t = 0; t < 10; ++t) {
    if (t < nct) {
      const int col = (ct0 + t) * 16 + ocol0;
      if (col < HID_) {
#pragma unroll
        for (int r = 0; r < 4; ++r) {
          float v = acc[t][r];
          if (ACT == 2) v = eluf(v);
          C[(size_t)(orow + r) * HID_ + col] = v;
        }
      }
    }
  }
}

// Split-K partial GEMM for small-M matmuls: grid (M/ROWS, KSPLIT).
template <int ROWS, int KSPLIT>
__global__ void gemm_skp(const float* __restrict__ A, const float* __restrict__ Bm,
                         float* __restrict__ P, int M, int K, int N) {
  const int c = threadIdx.x;
  const int r0 = blockIdx.x * ROWS;
  const int ks = blockIdx.y;
  if (c >= N) return;
  const int kchunk = (K + KSPLIT - 1) / KSPLIT;
  const int k0 = ks * kchunk;
  const int k1 = (k0 + kchunk < K) ? (k0 + kchunk) : K;
  float acc[ROWS];
#pragma unroll
  for (int r = 0; r < ROWS; ++r) acc[r] = 0.f;
  int k = k0;
  for (; k + 3 < k1; k += 4) {
    const float b0 = Bm[(size_t)(k + 0) * N + c];
    const float b1 = Bm[(size_t)(k + 1) * N + c];
    const float b2 = Bm[(size_t)(k + 2) * N + c];
    const float b3 = Bm[(size_t)(k + 3) * N + c];
#pragma unroll
    for (int r = 0; r < ROWS; ++r) {
      float4 a = ld4u(A + (size_t)(r0 + r) * K + k);
      acc[r] = fmaf(a.x, b0, acc[r]);
      acc[r] = fmaf(a.y, b1, acc[r]);
      acc[r] = fmaf(a.z, b2, acc[r]);
      acc[r] = fmaf(a.w, b3, acc[r]);
    }
  }
  for (; k < k1; ++k) {
    const float bv = Bm[(size_t)k * N + c];
#pragma unroll
    for (int r = 0; r < ROWS; ++r)
      acc[r] = fmaf(A[(size_t)(r0 + r) * K + k], bv, acc[r]);
  }
#pragma unroll
  for (int r = 0; r < ROWS; ++r)
    P[((size_t)ks * M + r0 + r) * N + c] = acc[r];
}

// Reduce split-K partials + bias + act. act: 0 none, 1 relu.
template <int KSPLIT>
__global__ void k_red(const float* __restrict__ P, const float* __restrict__ bias,
                      float* __restrict__ C, int M, int N, int ldc, int act) {
  const int idx = blockIdx.x * 256 + threadIdx.x;
  if (idx >= M * N) return;
  const int m = idx / N, c = idx - m * N;
  float v = 0.f;
#pragma unroll
  for (int p = 0; p < KSPLIT; ++p) v += P[(size_t)p * M * N + idx];
  if (bias) v += bias[c];
  if (act == 1) v = fmaxf(v, 0.f);
  C[(size_t)m * ldc + c] = v;
}

// K4: s2/d2 = Wh2 @ a_out halves. One wave per row.
__global__ __launch_bounds__(256) void k4_sd2(
    const float* __restrict__ Wh2, const float* __restrict__ ao,
    float* __restrict__ s2, float* __restrict__ d2) {
  const int lane = threadIdx.x & 63;
  const int row = blockIdx.x * 4 + (threadIdx.x >> 6);
  const float* wrow = Wh2 + (size_t)row * HID_;
  float as = 0.f, ad = 0.f;
  for (int c = lane; c < HID_; c += 64) {
    float v = wrow[c];
    as = fmaf(v, ao[c], as);
    ad = fmaf(v, ao[HID_ + c], ad);
  }
  as = wred_sum(as);
  ad = wred_sum(ad);
  if (lane == 0) { s2[row] = as; d2[row] = ad; }
}

// K5: attn2 probabilities p2[b,i,j]. One wave per row i.
__global__ __launch_bounds__(256) void k5_p2(
    const float* __restrict__ s2, const float* __restrict__ d2,
    const int* __restrict__ adj, float* __restrict__ p2) {
  const int lane = threadIdx.x & 63;
  const int row = blockIdx.x * 4 + (threadIdx.x >> 6);  // b*N+i
  const int b = row >> 7;
  float sv = s2[row];
  const float* drow = d2 + (size_t)b * N_;
  const int* arow = adj + (size_t)row * N_;
  float dv0 = drow[lane], dv1 = drow[64 + lane];
  int a0 = arow[lane], a1i = arow[64 + lane];
  float e0 = a0 > 0 ? lrelu(sv + dv0) : NEG_;
  float e1 = a1i > 0 ? lrelu(sv + dv1) : NEG_;
  float mx = wred_max(fmaxf(e0, e1));
  float x0 = expf(e0 - mx), x1 = expf(e1 - mx);
  float inv = 1.f / wred_sum(x0 + x1);
  p2[(size_t)row * N_ + lane] = x0 * inv;
  p2[(size_t)row * N_ + 64 + lane] = x1 * inv;
}

// K7: per-row max and log-sum-exp over 300 cols. One wave per row.
__global__ __launch_bounds__(256) void k7_lse(
    const float* __restrict__ ob, float* __restrict__ mx, float* __restrict__ ls) {
  const int lane = threadIdx.x & 63;
  const int row = blockIdx.x * 4 + (threadIdx.x >> 6);
  const float* orow = ob + (size_t)row * HID_;
  float v[5], m = -1e30f;
#pragma unroll
  for (int q = 0; q < 5; ++q) {
    int c = lane + q * 64;
    v[q] = (c < HID_) ? orow[c] : -1e30f;
    m = fmaxf(m, v[q]);
  }
  m = wred_max(m);
  float s = 0.f;
#pragma unroll
  for (int q = 0; q < 5; ++q) {
    int c = lane + q * 64;
    if (c < HID_) s += expf(v[q] - m);
  }
  s = wred_sum(s);
  if (lane == 0) { mx[row] = m; ls[row] = logf(s); }
}

// K8: gat_out[b,c] = mean_i (ob[b,i,c] - mx - ls). grid 256, block 320.
__global__ void k8_mean(const float* __restrict__ ob, const float* __restrict__ mx,
                        const float* __restrict__ ls, float* __restrict__ gat) {
  const int c = threadIdx.x;
  const int b = blockIdx.x;
  if (c >= HID_) return;
  float acc = 0.f;
  for (int i = 0; i < N_; ++i) {
    int row = b * N_ + i;
    acc += ob[(size_t)row * HID_ + c] - mx[row] - ls[row];
  }
  gat[(size_t)b * HID_ + c] = acc * (1.f / N_);
}

// out[b] = sigmoid(y[b,:] @ ffn_w2 + b2). One wave per row.
__global__ __launch_bounds__(256) void k_final(
    const float* __restrict__ y, const float* __restrict__ w2,
    const float* __restrict__ b2, float* __restrict__ out) {
  const int lane = threadIdx.x & 63;
  const int b = blockIdx.x * 4 + (threadIdx.x >> 6);
  float acc = 0.f;
  for (int c = lane; c < HID_; c += 64)
    acc = fmaf(y[(size_t)b * HID_ + c], w2[c], acc);
  acc = wred_sum(acc);
  if (lane == 0) out[b] = 1.f / (1.f + expf(-(acc + b2[0])));
}

extern "C" void kernel_launch(void* const* d_in, const int* in_sizes, int n_in,
                              void* d_out, int out_size, void* d_ws, size_t ws_size,
                              hipStream_t stream) {
  const float* atom  = (const float*)d_in[0];
  const float* fp    = (const float*)d_in[1];
  const float* Whead = (const float*)d_in[2];
  const float* ah    = (const float*)d_in[3];
  const float* Wout  = (const float*)d_in[4];
  const float* aout  = (const float*)d_in[5];
  const float* fc1w  = (const float*)d_in[6];
  const float* fc1b  = (const float*)d_in[7];
  const float* fc2w  = (const float*)d_in[8];
  const float* fc2b  = (const float*)d_in[9];
  const float* fgw   = (const float*)d_in[10];
  const float* fgb   = (const float*)d_in[11];
  const float* ffw   = (const float*)d_in[12];
  const float* ffb   = (const float*)d_in[13];
  const float* w1    = (const float*)d_in[14];
  const float* b1    = (const float*)d_in[15];
  const float* w2    = (const float*)d_in[16];
  const float* b2    = (const float*)d_in[17];
  const int*   adj   = (const int*)d_in[18];
  float* out = (float*)d_out;

  float* ws = (float*)d_ws;
  // Aliased layout (peak ~139 MB of floats):
  float* Wh   = ws;                       // 16,777,216   [K1 w, K2 r]
  float* Wh2  = ws;                       //  9,830,400   [K3 w .. K6 r]  (Wh dead)
  float* pbuf = ws;                       // <=1,048,576  [split-K partials; only
                                          //  live before k1 and after k8]
  float* p2   = ws + 9830400;             //  4,194,304   [K5 w, K6 r]
  float* sb   = ws + 16777216;            //    262,144
  float* db   = ws + 17039360;            //    262,144
  float* hb   = ws + 17301504;            // 16,777,216   [K2 w, K3 r]
  float* ob   = ws + 17301504;            //  9,830,400   [K6 w ..]  (hb dead)
  float* s2   = ws + 34078720;
  float* d2   = s2 + 32768;
  float* mxb  = d2 + 32768;
  float* lsb  = mxb + 32768;
  float* gat  = lsb + 32768;              //  76,800
  float* fpn1 = gat + 76800;              // 131,072
  float* fpn2 = fpn1 + 131072;            //  76,800
  float* xcat = fpn2 + 76800;             // 153,600
  float* yb   = xcat + 153600;            //  76,800

  // FPN branch (before k1 so pbuf aliasing of Wh region is safe)
  gemm_skp<4, 8><<<dim3(64, 8), 512, 0, stream>>>(fp, fc1w, pbuf, B_, FPD_, FP2_);
  k_red<8><<<512, 256, 0, stream>>>(pbuf, fc1b, fpn1, B_, FP2_, FP2_, 1);
  gemm_skp<4, 4><<<dim3(64, 4), 320, 0, stream>>>(fpn1, fc2w, pbuf, B_, FP2_, HID_);
  k_red<4><<<300, 256, 0, stream>>>(pbuf, fc2b, fpn2, B_, HID_, HID_, 0);

  // GAT stage 1
  k1_wh<<<2048, 512, 0, stream>>>(atom, Whead, ah, Wh, sb, db);
  k2_attn1<<<2048, 512, 0, stream>>>(Wh, sb, db, adj, hb);

  // Wh2 = h @ W_out  (M=32768, K=512, N=300) — MFMA split-bf16
  gemm_mfma<512, 0, false><<<1024, 256, 0, stream>>>(hb, Wout, Wh2);

  // GAT stage 2
  k4_sd2<<<8192, 256, 0, stream>>>(Wh2, aout, s2, d2);
  k5_p2<<<8192, 256, 0, stream>>>(s2, d2, adj, p2);
  // ob = elu(p2 @ Wh2)  (M=32768, K=128, N=300, B batched per 128 rows)
  gemm_mfma<128, 2, true><<<1024, 256, 0, stream>>>(p2, Wh2, ob);
  k7_lse<<<8192, 256, 0, stream>>>(ob, mxb, lsb);
  k8_mean<<<256, 320, 0, stream>>>(ob, mxb, lsb, gat);

  // Head (after k8: entire low ws region dead -> pbuf reuse is safe)
  gemm_skp<4, 4><<<dim3(64, 4), 320, 0, stream>>>(gat, fgw, pbuf, B_, HID_, HID_);
  k_red<4><<<300, 256, 0, stream>>>(pbuf, fgb, xcat, B_, HID_, 2 * HID_, 1);
  gemm_skp<4, 4><<<dim3(64, 4), 320, 0, stream>>>(fpn2, ffw, pbuf, B_, HID_, HID_);
  k_red<4><<<300, 256, 0, stream>>>(pbuf, ffb, xcat + 300, B_, HID_, 2 * HID_, 1);
  gemm_skp<4, 4><<<dim3(64, 4), 320, 0, stream>>>(xcat, w1, pbuf, B_, 2 * HID_, HID_);
  k_red<4><<<300, 256, 0, stream>>>(pbuf, b1, yb, B_, HID_, HID_, 1);
  k_final<<<64, 256, 0, stream>>>(yb, w2, b2, out);
}

// Round 11
// 433.939 us; speedup vs baseline: 2.5003x; 1.0565x over previous
//
#include <hip/hip_runtime.h>
#include <math.h>

// Problem constants
#define B_    256
#define N_    128
#define F_    133
#define H_    8
#define ND_   64     // NHID
#define HID_  300
#define FPD_  1489
#define FP2_  512
#define ALPHA_ 0.2f
#define NEG_  -9.0e15f

typedef __bf16 bf16x8 __attribute__((ext_vector_type(8)));
typedef float f32x4 __attribute__((ext_vector_type(4)));

__device__ __forceinline__ float wred_sum(float v) {
#pragma unroll
  for (int m = 32; m >= 1; m >>= 1) v += __shfl_xor(v, m, 64);
  return v;
}
__device__ __forceinline__ float wred_max(float v) {
#pragma unroll
  for (int m = 32; m >= 1; m >>= 1) v = fmaxf(v, __shfl_xor(v, m, 64));
  return v;
}
__device__ __forceinline__ float lrelu(float x) { return x > 0.f ? x : ALPHA_ * x; }
__device__ __forceinline__ float eluf(float x)  { return x > 0.f ? x : expf(x) - 1.f; }
// 16B load at 4B alignment (safe form)
__device__ __forceinline__ float4 ld4u(const float* p) {
  float4 v;
  __builtin_memcpy(&v, p, 16);
  return v;
}

// K1 (MFMA): Wh[b,h,n,d] = sum_f A[b,n,f] * W[h,f,d] via split-bf16 MFMA.
// Block = 128 rows x 1 head, 512 thr / 8 waves (wave = 16-row strip).
// W[h] staged transposed in LDS [64][168] bf16 hi/lo (k zero-padded 133->160+,
// pitch 168 -> ds_read_b128 covers all 32 banks across 16 lanes, 2-way free).
// K: 4 full 32-chunks + guarded 5-tail chunk. 128-row block == one batch b.
__global__ __launch_bounds__(512) void k1_mfma(
    const float* __restrict__ A, const float* __restrict__ W,
    float* __restrict__ Wh) {
  __shared__ __align__(16) __bf16 wth[64 * 168];
  __shared__ __align__(16) __bf16 wtl[64 * 168];
  const int tid = threadIdx.x;
  const int lane = tid & 63;
  const int wv = tid >> 6;
  const int h = blockIdx.y;
  const int m0 = blockIdx.x * 128;

  // Stage W[h] transposed + split + zero-pad.
  {
    const float* Wg = W + (size_t)h * F_ * ND_;
    const int d = tid >> 3;        // 64 d-values x 8 threads
    const int kq = tid & 7;
    for (int k = kq; k < 168; k += 8) {
      float v = (k < F_) ? Wg[k * ND_ + d] : 0.f;
      __bf16 hv = (__bf16)v;
      wth[d * 168 + k] = hv;
      wtl[d * 168 + k] = (__bf16)(v - (float)hv);
    }
  }
  __syncthreads();

  const int mrow = m0 + wv * 16 + (lane & 15);
  const float* Ap = A + (size_t)mrow * F_;
  f32x4 acc[4];
#pragma unroll
  for (int t = 0; t < 4; ++t) acc[t] = f32x4{0.f, 0.f, 0.f, 0.f};

#pragma unroll
  for (int ks = 0; ks < 5; ++ks) {
    const int kb = ks * 32 + (lane >> 4) * 8;
    float av[8];
    if (ks < 4) {
      float4 a0 = ld4u(Ap + kb);
      float4 a1 = ld4u(Ap + kb + 4);
      av[0] = a0.x; av[1] = a0.y; av[2] = a0.z; av[3] = a0.w;
      av[4] = a1.x; av[5] = a1.y; av[6] = a1.z; av[7] = a1.w;
    } else {
#pragma unroll
      for (int j = 0; j < 8; ++j)
        av[j] = (kb + j < F_) ? Ap[kb + j] : 0.f;
    }
    bf16x8 ah8, al8;
#pragma unroll
    for (int j = 0; j < 8; ++j) {
      float v = av[j];
      __bf16 hv = (__bf16)v;
      ah8[j] = hv;
      al8[j] = (__bf16)(v - (float)hv);
    }
#pragma unroll
    for (int ct = 0; ct < 4; ++ct) {
      const int d = ct * 16 + (lane & 15);
      bf16x8 bh8 = *reinterpret_cast<const bf16x8*>(&wth[d * 168 + kb]);
      bf16x8 bl8 = *reinterpret_cast<const bf16x8*>(&wtl[d * 168 + kb]);
      acc[ct] = __builtin_amdgcn_mfma_f32_16x16x32_bf16(al8, bh8, acc[ct], 0, 0, 0);
      acc[ct] = __builtin_amdgcn_mfma_f32_16x16x32_bf16(ah8, bl8, acc[ct], 0, 0, 0);
      acc[ct] = __builtin_amdgcn_mfma_f32_16x16x32_bf16(ah8, bh8, acc[ct], 0, 0, 0);
    }
  }

  // Output: block's rows are batch b = blockIdx.x; n = row & 127.
  float* Whb = Wh + (((size_t)blockIdx.x * H_ + h) * N_) * ND_;
  const int n0 = wv * 16 + (lane >> 4) * 4;
#pragma unroll
  for (int ct = 0; ct < 4; ++ct) {
    const int d = ct * 16 + (lane & 15);
#pragma unroll
    for (int r = 0; r < 4; ++r)
      Whb[(size_t)(n0 + r) * ND_ + d] = acc[ct][r];
  }
}

// K2: masked softmax + h = elu(attn @ Wh) via MFMA; s/d projections fused
// into the staging pass (sf/df in LDS — no global sb/db).
// One block = one (b,h) panel. 512 thr / 8 waves.
__global__ __launch_bounds__(512) void k2_attn1(
    const float* __restrict__ Wh, const float* __restrict__ ahp,
    const int* __restrict__ adj, float* __restrict__ hb) {
  __shared__ __align__(16) __bf16 ph[128 * 136];
  __shared__ __align__(16) __bf16 pl[128 * 136];
  __shared__ __align__(16) __bf16 wth[64 * 136];
  __shared__ __align__(16) __bf16 wtl[64 * 136];
  __shared__ float sf[128], df[128];
  const int tid = threadIdx.x;
  const int lane = tid & 63;
  const int w = tid >> 6;           // wave 0..7
  const int bh = blockIdx.x;
  const int b = bh >> 3, h = bh & 7;

  // Phase 0: stage Wh panel transposed + split-bf16; fuse s/d row sums.
  {
    const float a1 = ahp[h * 2 * ND_ + lane];
    const float a2 = ahp[h * 2 * ND_ + ND_ + lane];
    const float* Whp = Wh + (size_t)bh * N_ * ND_;
#pragma unroll
    for (int iter = 0; iter < 16; ++iter) {
      const int idx = iter * 512 + tid;
      const int j = idx >> 6;       // row (== w + iter*8 for this wave)
      float v = Whp[idx];
      __bf16 hv = (__bf16)v;
      wth[lane * 136 + j] = hv;
      wtl[lane * 136 + j] = (__bf16)(v - (float)hv);
      float sv = wred_sum(v * a1);
      float dv = wred_sum(v * a2);
      if (lane == 0) { sf[j] = sv; df[j] = dv; }
    }
  }
  __syncthreads();

  // Phase 1: masked softmax for rows w*16 .. w*16+15.
  {
    const float dv0 = df[lane];
    const float dv1 = df[64 + lane];
    const int i0 = w * 16;
    int a0v[16], a1v[16];
#pragma unroll
    for (int r = 0; r < 16; ++r) {
      const int* arow = adj + ((size_t)b * N_ + i0 + r) * N_;
      a0v[r] = arow[lane];
      a1v[r] = arow[64 + lane];
    }
#pragma unroll
    for (int r = 0; r < 16; ++r) {
      const int i = i0 + r;
      const float sv = sf[i];
      float e0 = a0v[r] > 0 ? lrelu(sv + dv0) : NEG_;
      float e1 = a1v[r] > 0 ? lrelu(sv + dv1) : NEG_;
      float mx = wred_max(fmaxf(e0, e1));
      float x0 = expf(e0 - mx), x1 = expf(e1 - mx);
      float inv = 1.f / wred_sum(x0 + x1);
      float p0 = x0 * inv, p1 = x1 * inv;
      __bf16 h0 = (__bf16)p0, h1 = (__bf16)p1;
      ph[i * 136 + lane] = h0;
      ph[i * 136 + 64 + lane] = h1;
      pl[i * 136 + lane] = (__bf16)(p0 - (float)h0);
      pl[i * 136 + 64 + lane] = (__bf16)(p1 - (float)h1);
    }
  }
  __syncthreads();

  // Phase 2: strip rows m0..m0+15 = p_strip(16x128) @ Wh(128x64), MFMA.
  {
    const int m0 = w * 16;
    const int arow = m0 + (lane & 15);
    f32x4 acc[4];
#pragma unroll
    for (int t = 0; t < 4; ++t) acc[t] = f32x4{0.f, 0.f, 0.f, 0.f};
#pragma unroll
    for (int ks = 0; ks < 4; ++ks) {
      const int kb = ks * 32 + (lane >> 4) * 8;
      bf16x8 ah8 = *reinterpret_cast<const bf16x8*>(&ph[arow * 136 + kb]);
      bf16x8 al8 = *reinterpret_cast<const bf16x8*>(&pl[arow * 136 + kb]);
#pragma unroll
      for (int ct = 0; ct < 4; ++ct) {
        const int col = ct * 16 + (lane & 15);
        bf16x8 bh8 = *reinterpret_cast<const bf16x8*>(&wth[col * 136 + kb]);
        bf16x8 bl8 = *reinterpret_cast<const bf16x8*>(&wtl[col * 136 + kb]);
        acc[ct] = __builtin_amdgcn_mfma_f32_16x16x32_bf16(al8, bh8, acc[ct], 0, 0, 0);
        acc[ct] = __builtin_amdgcn_mfma_f32_16x16x32_bf16(ah8, bl8, acc[ct], 0, 0, 0);
        acc[ct] = __builtin_amdgcn_mfma_f32_16x16x32_bf16(ah8, bh8, acc[ct], 0, 0, 0);
      }
    }
    const int orow0 = m0 + (lane >> 4) * 4;
#pragma unroll
    for (int ct = 0; ct < 4; ++ct) {
      const int d = ct * 16 + (lane & 15);
#pragma unroll
      for (int r = 0; r < 4; ++r) {
        const int i = orow0 + r;
        hb[((size_t)b * N_ + i) * (H_ * ND_) + h * ND_ + d] = eluf(acc[ct][r]);
      }
    }
  }
}

// MFMA split-bf16 GEMM: C = act(A @ B), A MxK fp32 (K%32==0), B KxN fp32,
// N=300. D ~= Al*Bh + Ah*Bl + Ah*Bh accumulated fp32.
// Wave = 16 rows x colhalf (10 or 9 tiles of 16x16). Block 256 thr = 4 waves
// (2 row-strips x 2 colhalves), BM=32, grid M/32=1024. No LDS.
template <int K, int ACT, bool BATB>
__global__ __launch_bounds__(256) void gemm_mfma(
    const float* __restrict__ A, const float* __restrict__ Bm,
    float* __restrict__ C) {
  const int tid = threadIdx.x;
  const int lane = tid & 63;
  const int wv = tid >> 6;
  const int rs = wv >> 1;           // row-strip in block
  const int ch = wv & 1;            // col-half
  const int m0 = blockIdx.x * 32 + rs * 16;
  const float* Ap = A + (size_t)(m0 + (lane & 15)) * K + ((lane >> 4) * 8);
  const float* Bp = BATB ? Bm + (size_t)(m0 >> 7) * K * HID_ : Bm;
  const int ct0 = ch * 10;
  const int nct = ch ? 9 : 10;      // tiles 0..9 / 10..18 (col 160..299)
  f32x4 acc[10];
#pragma unroll
  for (int t = 0; t < 10; ++t) acc[t] = f32x4{0.f, 0.f, 0.f, 0.f};

  for (int ks = 0; ks < K / 32; ++ks) {
    float4 a0 = *reinterpret_cast<const float4*>(Ap + ks * 32);
    float4 a1 = *reinterpret_cast<const float4*>(Ap + ks * 32 + 4);
    float av[8] = {a0.x, a0.y, a0.z, a0.w, a1.x, a1.y, a1.z, a1.w};
    bf16x8 ah, al;
#pragma unroll
    for (int j = 0; j < 8; ++j) {
      float v = av[j];
      __bf16 hv = (__bf16)v;
      ah[j] = hv;
      al[j] = (__bf16)(v - (float)hv);
    }
    const int kb = ks * 32 + (lane >> 4) * 8;
#pragma unroll
    for (int t = 0; t < 10; ++t) {
      if (t < nct) {
        const int col = (ct0 + t) * 16 + (lane & 15);
        const bool cv = col < HID_;
        const float* Bc = Bp + (size_t)kb * HID_ + col;
        float bv[8];
#pragma unroll
        for (int i = 0; i < 8; ++i) bv[i] = cv ? Bc[(size_t)i * HID_] : 0.f;
        bf16x8 bh, bl;
#pragma unroll
        for (int j = 0; j < 8; ++j) {
          float v = bv[j];
          __bf16 hv = (__bf16)v;
          bh[j] = hv;
          bl[j] = (__bf16)(v - (float)hv);
        }
        acc[t] = __builtin_amdgcn_mfma_f32_16x16x32_bf16(al, bh, acc[t], 0, 0, 0);
        acc[t] = __builtin_amdgcn_mfma_f32_16x16x32_bf16(ah, bl, acc[t], 0, 0, 0);
        acc[t] = __builtin_amdgcn_mfma_f32_16x16x32_bf16(ah, bh, acc[t], 0, 0, 0);
      }
    }
  }

  const int orow = m0 + (lane >> 4) * 4;
  const int ocol0 = (lane & 15);
#pragma unroll
  for (int t = 0; t < 10; ++t) {
    if (t < nct) {
      const int col = (ct0 + t) * 16 + ocol0;
      if (col < HID_) {
#pragma unroll
        for (int r = 0; r < 4; ++r) {
          float v = acc[t][r];
          if (ACT == 2) v = eluf(v);
          C[(size_t)(orow + r) * HID_ + col] = v;
        }
      }
    }
  }
}

// Split-K partial GEMM for small-M matmuls: grid (M/ROWS, KSPLIT).
template <int ROWS, int KSPLIT>
__global__ void gemm_skp(const float* __restrict__ A, const float* __restrict__ Bm,
                         float* __restrict__ P, int M, int K, int N) {
  const int c = threadIdx.x;
  const int r0 = blockIdx.x * ROWS;
  const int ks = blockIdx.y;
  if (c >= N) return;
  const int kchunk = (K + KSPLIT - 1) / KSPLIT;
  const int k0 = ks * kchunk;
  const int k1 = (k0 + kchunk < K) ? (k0 + kchunk) : K;
  float acc[ROWS];
#pragma unroll
  for (int r = 0; r < ROWS; ++r) acc[r] = 0.f;
  int k = k0;
  for (; k + 3 < k1; k += 4) {
    const float b0 = Bm[(size_t)(k + 0) * N + c];
    const float b1 = Bm[(size_t)(k + 1) * N + c];
    const float b2 = Bm[(size_t)(k + 2) * N + c];
    const float b3 = Bm[(size_t)(k + 3) * N + c];
#pragma unroll
    for (int r = 0; r < ROWS; ++r) {
      float4 a = ld4u(A + (size_t)(r0 + r) * K + k);
      acc[r] = fmaf(a.x, b0, acc[r]);
      acc[r] = fmaf(a.y, b1, acc[r]);
      acc[r] = fmaf(a.z, b2, acc[r]);
      acc[r] = fmaf(a.w, b3, acc[r]);
    }
  }
  for (; k < k1; ++k) {
    const float bv = Bm[(size_t)k * N + c];
#pragma unroll
    for (int r = 0; r < ROWS; ++r)
      acc[r] = fmaf(A[(size_t)(r0 + r) * K + k], bv, acc[r]);
  }
#pragma unroll
  for (int r = 0; r < ROWS; ++r)
    P[((size_t)ks * M + r0 + r) * N + c] = acc[r];
}

// Reduce split-K partials + bias + act. act: 0 none, 1 relu.
template <int KSPLIT>
__global__ void k_red(const float* __restrict__ P, const float* __restrict__ bias,
                      float* __restrict__ C, int M, int N, int ldc, int act) {
  const int idx = blockIdx.x * 256 + threadIdx.x;
  if (idx >= M * N) return;
  const int m = idx / N, c = idx - m * N;
  float v = 0.f;
#pragma unroll
  for (int p = 0; p < KSPLIT; ++p) v += P[(size_t)p * M * N + idx];
  if (bias) v += bias[c];
  if (act == 1) v = fmaxf(v, 0.f);
  C[(size_t)m * ldc + c] = v;
}

// K4: s2/d2 = Wh2 @ a_out halves. One wave per row.
__global__ __launch_bounds__(256) void k4_sd2(
    const float* __restrict__ Wh2, const float* __restrict__ ao,
    float* __restrict__ s2, float* __restrict__ d2) {
  const int lane = threadIdx.x & 63;
  const int row = blockIdx.x * 4 + (threadIdx.x >> 6);
  const float* wrow = Wh2 + (size_t)row * HID_;
  float as = 0.f, ad = 0.f;
  for (int c = lane; c < HID_; c += 64) {
    float v = wrow[c];
    as = fmaf(v, ao[c], as);
    ad = fmaf(v, ao[HID_ + c], ad);
  }
  as = wred_sum(as);
  ad = wred_sum(ad);
  if (lane == 0) { s2[row] = as; d2[row] = ad; }
}

// K5: attn2 probabilities p2[b,i,j]. One wave per row i.
__global__ __launch_bounds__(256) void k5_p2(
    const float* __restrict__ s2, const float* __restrict__ d2,
    const int* __restrict__ adj, float* __restrict__ p2) {
  const int lane = threadIdx.x & 63;
  const int row = blockIdx.x * 4 + (threadIdx.x >> 6);  // b*N+i
  const int b = row >> 7;
  float sv = s2[row];
  const float* drow = d2 + (size_t)b * N_;
  const int* arow = adj + (size_t)row * N_;
  float dv0 = drow[lane], dv1 = drow[64 + lane];
  int a0 = arow[lane], a1i = arow[64 + lane];
  float e0 = a0 > 0 ? lrelu(sv + dv0) : NEG_;
  float e1 = a1i > 0 ? lrelu(sv + dv1) : NEG_;
  float mx = wred_max(fmaxf(e0, e1));
  float x0 = expf(e0 - mx), x1 = expf(e1 - mx);
  float inv = 1.f / wred_sum(x0 + x1);
  p2[(size_t)row * N_ + lane] = x0 * inv;
  p2[(size_t)row * N_ + 64 + lane] = x1 * inv;
}

// K7: per-row max and log-sum-exp over 300 cols. One wave per row.
__global__ __launch_bounds__(256) void k7_lse(
    const float* __restrict__ ob, float* __restrict__ mx, float* __restrict__ ls) {
  const int lane = threadIdx.x & 63;
  const int row = blockIdx.x * 4 + (threadIdx.x >> 6);
  const float* orow = ob + (size_t)row * HID_;
  float v[5], m = -1e30f;
#pragma unroll
  for (int q = 0; q < 5; ++q) {
    int c = lane + q * 64;
    v[q] = (c < HID_) ? orow[c] : -1e30f;
    m = fmaxf(m, v[q]);
  }
  m = wred_max(m);
  float s = 0.f;
#pragma unroll
  for (int q = 0; q < 5; ++q) {
    int c = lane + q * 64;
    if (c < HID_) s += expf(v[q] - m);
  }
  s = wred_sum(s);
  if (lane == 0) { mx[row] = m; ls[row] = logf(s); }
}

// K8: gat_out[b,c] = mean_i (ob[b,i,c] - mx - ls). grid 256, block 320.
__global__ void k8_mean(const float* __restrict__ ob, const float* __restrict__ mx,
                        const float* __restrict__ ls, float* __restrict__ gat) {
  const int c = threadIdx.x;
  const int b = blockIdx.x;
  if (c >= HID_) return;
  float acc = 0.f;
  for (int i = 0; i < N_; ++i) {
    int row = b * N_ + i;
    acc += ob[(size_t)row * HID_ + c] - mx[row] - ls[row];
  }
  gat[(size_t)b * HID_ + c] = acc * (1.f / N_);
}

// out[b] = sigmoid(y[b,:] @ ffn_w2 + b2). One wave per row.
__global__ __launch_bounds__(256) void k_final(
    const float* __restrict__ y, const float* __restrict__ w2,
    const float* __restrict__ b2, float* __restrict__ out) {
  const int lane = threadIdx.x & 63;
  const int b = blockIdx.x * 4 + (threadIdx.x >> 6);
  float acc = 0.f;
  for (int c = lane; c < HID_; c += 64)
    acc = fmaf(y[(size_t)b * HID_ + c], w2[c], acc);
  acc = wred_sum(acc);
  if (lane == 0) out[b] = 1.f / (1.f + expf(-(acc + b2[0])));
}

extern "C" void kernel_launch(void* const* d_in, const int* in_sizes, int n_in,
                              void* d_out, int out_size, void* d_ws, size_t ws_size,
                              hipStream_t stream) {
  const float* atom  = (const float*)d_in[0];
  const float* fp    = (const float*)d_in[1];
  const float* Whead = (const float*)d_in[2];
  const float* ah    = (const float*)d_in[3];
  const float* Wout  = (const float*)d_in[4];
  const float* aout  = (const float*)d_in[5];
  const float* fc1w  = (const float*)d_in[6];
  const float* fc1b  = (const float*)d_in[7];
  const float* fc2w  = (const float*)d_in[8];
  const float* fc2b  = (const float*)d_in[9];
  const float* fgw   = (const float*)d_in[10];
  const float* fgb   = (const float*)d_in[11];
  const float* ffw   = (const float*)d_in[12];
  const float* ffb   = (const float*)d_in[13];
  const float* w1    = (const float*)d_in[14];
  const float* b1    = (const float*)d_in[15];
  const float* w2    = (const float*)d_in[16];
  const float* b2    = (const float*)d_in[17];
  const int*   adj   = (const int*)d_in[18];
  float* out = (float*)d_out;

  float* ws = (float*)d_ws;
  // Aliased layout (peak ~139 MB of floats):
  float* Wh   = ws;                       // 16,777,216   [K1 w, K2 r]
  float* Wh2  = ws;                       //  9,830,400   [K3 w .. K6 r]  (Wh dead)
  float* pbuf = ws;                       // <=1,048,576  [split-K partials; only
                                          //  live before k1 and after k8]
  float* p2   = ws + 9830400;             //  4,194,304   [K5 w, K6 r]
  float* hb   = ws + 17301504;            // 16,777,216   [K2 w, K3 r]
  float* ob   = ws + 17301504;            //  9,830,400   [K6 w ..]  (hb dead)
  float* s2   = ws + 34078720;
  float* d2   = s2 + 32768;
  float* mxb  = d2 + 32768;
  float* lsb  = mxb + 32768;
  float* gat  = lsb + 32768;              //  76,800
  float* fpn1 = gat + 76800;              // 131,072
  float* fpn2 = fpn1 + 131072;            //  76,800
  float* xcat = fpn2 + 76800;             // 153,600
  float* yb   = xcat + 153600;            //  76,800

  // FPN branch (before k1 so pbuf aliasing of Wh region is safe)
  gemm_skp<4, 8><<<dim3(64, 8), 512, 0, stream>>>(fp, fc1w, pbuf, B_, FPD_, FP2_);
  k_red<8><<<512, 256, 0, stream>>>(pbuf, fc1b, fpn1, B_, FP2_, FP2_, 1);
  gemm_skp<4, 4><<<dim3(64, 4), 320, 0, stream>>>(fpn1, fc2w, pbuf, B_, FP2_, HID_);
  k_red<4><<<300, 256, 0, stream>>>(pbuf, fc2b, fpn2, B_, HID_, HID_, 0);

  // GAT stage 1
  k1_mfma<<<dim3(256, 8), 512, 0, stream>>>(atom, Whead, Wh);
  k2_attn1<<<2048, 512, 0, stream>>>(Wh, ah, adj, hb);

  // Wh2 = h @ W_out  (M=32768, K=512, N=300) — MFMA split-bf16
  gemm_mfma<512, 0, false><<<1024, 256, 0, stream>>>(hb, Wout, Wh2);

  // GAT stage 2
  k4_sd2<<<8192, 256, 0, stream>>>(Wh2, aout, s2, d2);
  k5_p2<<<8192, 256, 0, stream>>>(s2, d2, adj, p2);
  // ob = elu(p2 @ Wh2)  (M=32768, K=128, N=300, B batched per 128 rows)
  gemm_mfma<128, 2, true><<<1024, 256, 0, stream>>>(p2, Wh2, ob);
  k7_lse<<<8192, 256, 0, stream>>>(ob, mxb, lsb);
  k8_mean<<<256, 320, 0, stream>>>(ob, mxb, lsb, gat);

  // Head (after k8: entire low ws region dead -> pbuf reuse is safe)
  gemm_skp<4, 4><<<dim3(64, 4), 320, 0, stream>>>(gat, fgw, pbuf, B_, HID_, HID_);
  k_red<4><<<300, 256, 0, stream>>>(pbuf, fgb, xcat, B_, HID_, 2 * HID_, 1);
  gemm_skp<4, 4><<<dim3(64, 4), 320, 0, stream>>>(fpn2, ffw, pbuf, B_, HID_, HID_);
  k_red<4><<<300, 256, 0, stream>>>(pbuf, ffb, xcat + 300, B_, HID_, 2 * HID_, 1);
  gemm_skp<4, 4><<<dim3(64, 4), 320, 0, stream>>>(xcat, w1, pbuf, B_, 2 * HID_, HID_);
  k_red<4><<<300, 256, 0, stream>>>(pbuf, b1, yb, B_, HID_, HID_, 1);
  k_final<<<64, 256, 0, stream>>>(yb, w2, b2, out);
}

// Round 12
// 359.685 us; speedup vs baseline: 3.0165x; 1.2064x over previous
//
#include <hip/hip_runtime.h>
#include <math.h>

// Problem constants
#define B_    256
#define N_    128
#define F_    133
#define H_    8
#define ND_   64     // NHID
#define HID_  300
#define FPD_  1489
#define FP2_  512
#define ALPHA_ 0.2f
#define NEG_  -9.0e15f

typedef __bf16 bf16x8 __attribute__((ext_vector_type(8)));
typedef float f32x4 __attribute__((ext_vector_type(4)));

__device__ __forceinline__ float wred_sum(float v) {
#pragma unroll
  for (int m = 32; m >= 1; m >>= 1) v += __shfl_xor(v, m, 64);
  return v;
}
__device__ __forceinline__ float wred_max(float v) {
#pragma unroll
  for (int m = 32; m >= 1; m >>= 1) v = fmaxf(v, __shfl_xor(v, m, 64));
  return v;
}
__device__ __forceinline__ float lrelu(float x) { return x > 0.f ? x : ALPHA_ * x; }
__device__ __forceinline__ float eluf(float x)  { return x > 0.f ? x : expf(x) - 1.f; }
// 16B load at 4B alignment (safe form)
__device__ __forceinline__ float4 ld4u(const float* p) {
  float4 v;
  __builtin_memcpy(&v, p, 16);
  return v;
}

// K1 (MFMA): Wh[b,h,n,d] = sum_f A[b,n,f] * W[h,f,d] via split-bf16 MFMA.
// Block = 128 rows x 1 head, 512 thr / 8 waves (wave = 16-row strip).
// Epilogue: s/d projections computed from acc registers (4 FMA + 4-step
// 16-lane shfl reduce per row) -> sb/db. 128-row block == one batch b.
__global__ __launch_bounds__(512) void k1_mfma(
    const float* __restrict__ A, const float* __restrict__ W,
    const float* __restrict__ ahp, float* __restrict__ Wh,
    float* __restrict__ sb, float* __restrict__ db) {
  __shared__ __align__(16) __bf16 wth[64 * 168];
  __shared__ __align__(16) __bf16 wtl[64 * 168];
  const int tid = threadIdx.x;
  const int lane = tid & 63;
  const int wv = tid >> 6;
  const int h = blockIdx.y;
  const int m0 = blockIdx.x * 128;

  // Stage W[h] transposed + split + zero-pad.
  {
    const float* Wg = W + (size_t)h * F_ * ND_;
    const int d = tid >> 3;        // 64 d-values x 8 threads
    const int kq = tid & 7;
    for (int k = kq; k < 168; k += 8) {
      float v = (k < F_) ? Wg[k * ND_ + d] : 0.f;
      __bf16 hv = (__bf16)v;
      wth[d * 168 + k] = hv;
      wtl[d * 168 + k] = (__bf16)(v - (float)hv);
    }
  }
  __syncthreads();

  const int mrow = m0 + wv * 16 + (lane & 15);
  const float* Ap = A + (size_t)mrow * F_;
  f32x4 acc[4];
#pragma unroll
  for (int t = 0; t < 4; ++t) acc[t] = f32x4{0.f, 0.f, 0.f, 0.f};

#pragma unroll
  for (int ks = 0; ks < 5; ++ks) {
    const int kb = ks * 32 + (lane >> 4) * 8;
    float av[8];
    if (ks < 4) {
      float4 a0 = ld4u(Ap + kb);
      float4 a1 = ld4u(Ap + kb + 4);
      av[0] = a0.x; av[1] = a0.y; av[2] = a0.z; av[3] = a0.w;
      av[4] = a1.x; av[5] = a1.y; av[6] = a1.z; av[7] = a1.w;
    } else {
#pragma unroll
      for (int j = 0; j < 8; ++j)
        av[j] = (kb + j < F_) ? Ap[kb + j] : 0.f;
    }
    bf16x8 ah8, al8;
#pragma unroll
    for (int j = 0; j < 8; ++j) {
      float v = av[j];
      __bf16 hv = (__bf16)v;
      ah8[j] = hv;
      al8[j] = (__bf16)(v - (float)hv);
    }
#pragma unroll
    for (int ct = 0; ct < 4; ++ct) {
      const int d = ct * 16 + (lane & 15);
      bf16x8 bh8 = *reinterpret_cast<const bf16x8*>(&wth[d * 168 + kb]);
      bf16x8 bl8 = *reinterpret_cast<const bf16x8*>(&wtl[d * 168 + kb]);
      acc[ct] = __builtin_amdgcn_mfma_f32_16x16x32_bf16(al8, bh8, acc[ct], 0, 0, 0);
      acc[ct] = __builtin_amdgcn_mfma_f32_16x16x32_bf16(ah8, bl8, acc[ct], 0, 0, 0);
      acc[ct] = __builtin_amdgcn_mfma_f32_16x16x32_bf16(ah8, bh8, acc[ct], 0, 0, 0);
    }
  }

  // Output: block's rows are batch b = blockIdx.x; n = row & 127.
  const size_t bh = (size_t)blockIdx.x * H_ + h;
  float* Whb = Wh + bh * N_ * ND_;
  const int n0 = wv * 16 + (lane >> 4) * 4;
#pragma unroll
  for (int ct = 0; ct < 4; ++ct) {
    const int d = ct * 16 + (lane & 15);
#pragma unroll
    for (int r = 0; r < 4; ++r)
      Whb[(size_t)(n0 + r) * ND_ + d] = acc[ct][r];
  }

  // s/d epilogue: s[n] = sum_d Wh[n][d]*a1[d]; d = ct*16+(lane&15).
  {
    float a1v[4], a2v[4];
#pragma unroll
    for (int ct = 0; ct < 4; ++ct) {
      a1v[ct] = ahp[h * 2 * ND_ + ct * 16 + (lane & 15)];
      a2v[ct] = ahp[h * 2 * ND_ + ND_ + ct * 16 + (lane & 15)];
    }
#pragma unroll
    for (int r = 0; r < 4; ++r) {
      float sv = 0.f, dv = 0.f;
#pragma unroll
      for (int ct = 0; ct < 4; ++ct) {
        sv = fmaf(acc[ct][r], a1v[ct], sv);
        dv = fmaf(acc[ct][r], a2v[ct], dv);
      }
#pragma unroll
      for (int m = 1; m <= 8; m <<= 1) {
        sv += __shfl_xor(sv, m, 64);
        dv += __shfl_xor(dv, m, 64);
      }
      if ((lane & 15) == 0) {
        sb[bh * N_ + n0 + r] = sv;
        db[bh * N_ + n0 + r] = dv;
      }
    }
  }
}

// K2: masked softmax + h = elu(attn @ Wh) via MFMA. Barrier-free:
// each wave softmaxes its own 16 rows into its private ph/pl LDS slice,
// then consumes only those rows as MFMA A-fragments. B-fragments read
// directly from global Wh (fp32, inline split-bf16; panel is L1-resident).
// LDS 69.6 KB -> 2 blocks/CU. One block = one (b,h). 512 thr / 8 waves.
__global__ __launch_bounds__(512) void k2_attn1(
    const float* __restrict__ Wh, const float* __restrict__ sb,
    const float* __restrict__ db, const int* __restrict__ adj,
    float* __restrict__ hb) {
  __shared__ __align__(16) __bf16 ph[128 * 136];
  __shared__ __align__(16) __bf16 pl[128 * 136];
  const int tid = threadIdx.x;
  const int lane = tid & 63;
  const int w = tid >> 6;           // wave 0..7
  const int bh = blockIdx.x;
  const int b = bh >> 3, h = bh & 7;
  const int i0 = w * 16;

  // Phase 1 (wave-private): masked softmax rows i0..i0+15 -> ph/pl.
  {
    const float dv0 = db[(size_t)bh * N_ + lane];
    const float dv1 = db[(size_t)bh * N_ + 64 + lane];
    int a0v[16], a1v[16];
#pragma unroll
    for (int r = 0; r < 16; ++r) {
      const int* arow = adj + ((size_t)b * N_ + i0 + r) * N_;
      a0v[r] = arow[lane];
      a1v[r] = arow[64 + lane];
    }
#pragma unroll
    for (int r = 0; r < 16; ++r) {
      const int i = i0 + r;
      const float sv = sb[(size_t)bh * N_ + i];
      float e0 = a0v[r] > 0 ? lrelu(sv + dv0) : NEG_;
      float e1 = a1v[r] > 0 ? lrelu(sv + dv1) : NEG_;
      float mx = wred_max(fmaxf(e0, e1));
      float x0 = expf(e0 - mx), x1 = expf(e1 - mx);
      float inv = 1.f / wred_sum(x0 + x1);
      float p0 = x0 * inv, p1 = x1 * inv;
      __bf16 h0 = (__bf16)p0, h1 = (__bf16)p1;
      ph[i * 136 + lane] = h0;
      ph[i * 136 + 64 + lane] = h1;
      pl[i * 136 + lane] = (__bf16)(p0 - (float)h0);
      pl[i * 136 + 64 + lane] = (__bf16)(p1 - (float)h1);
    }
  }
  // No __syncthreads: wave reads only rows it wrote (in-wave LDS ordering).

  // Phase 2: rows i0..i0+15 = p_strip(16x128) @ Wh(128x64), MFMA.
  {
    const int arow = i0 + (lane & 15);
    const float* Whp = Wh + (size_t)bh * N_ * ND_;
    f32x4 acc[4];
#pragma unroll
    for (int t = 0; t < 4; ++t) acc[t] = f32x4{0.f, 0.f, 0.f, 0.f};
#pragma unroll
    for (int ks = 0; ks < 4; ++ks) {
      const int kb = ks * 32 + (lane >> 4) * 8;
      bf16x8 ah8 = *reinterpret_cast<const bf16x8*>(&ph[arow * 136 + kb]);
      bf16x8 al8 = *reinterpret_cast<const bf16x8*>(&pl[arow * 136 + kb]);
#pragma unroll
      for (int ct = 0; ct < 4; ++ct) {
        const int d = ct * 16 + (lane & 15);
        const float* Bc = Whp + (size_t)kb * ND_ + d;
        float bv[8];
#pragma unroll
        for (int i = 0; i < 8; ++i) bv[i] = Bc[(size_t)i * ND_];
        bf16x8 bh8, bl8;
#pragma unroll
        for (int j = 0; j < 8; ++j) {
          float v = bv[j];
          __bf16 hv = (__bf16)v;
          bh8[j] = hv;
          bl8[j] = (__bf16)(v - (float)hv);
        }
        acc[ct] = __builtin_amdgcn_mfma_f32_16x16x32_bf16(al8, bh8, acc[ct], 0, 0, 0);
        acc[ct] = __builtin_amdgcn_mfma_f32_16x16x32_bf16(ah8, bl8, acc[ct], 0, 0, 0);
        acc[ct] = __builtin_amdgcn_mfma_f32_16x16x32_bf16(ah8, bh8, acc[ct], 0, 0, 0);
      }
    }
    const int orow0 = i0 + (lane >> 4) * 4;
#pragma unroll
    for (int ct = 0; ct < 4; ++ct) {
      const int d = ct * 16 + (lane & 15);
#pragma unroll
      for (int r = 0; r < 4; ++r) {
        const int i = orow0 + r;
        hb[((size_t)b * N_ + i) * (H_ * ND_) + h * ND_ + d] = eluf(acc[ct][r]);
      }
    }
  }
}

// MFMA split-bf16 GEMM: C = act(A @ B), A MxK fp32 (K%32==0), B KxN fp32,
// N=300. D ~= Al*Bh + Ah*Bl + Ah*Bh accumulated fp32.
// Wave = 16 rows x colhalf (10 or 9 tiles of 16x16). Block 256 thr = 4 waves
// (2 row-strips x 2 colhalves), BM=32, grid M/32=1024. No LDS.
template <int K, int ACT, bool BATB>
__global__ __launch_bounds__(256) void gemm_mfma(
    const float* __restrict__ A, const float* __restrict__ Bm,
    float* __restrict__ C) {
  const int tid = threadIdx.x;
  const int lane = tid & 63;
  const int wv = tid >> 6;
  const int rs = wv >> 1;           // row-strip in block
  const int ch = wv & 1;            // col-half
  const int m0 = blockIdx.x * 32 + rs * 16;
  const float* Ap = A + (size_t)(m0 + (lane & 15)) * K + ((lane >> 4) * 8);
  const float* Bp = BATB ? Bm + (size_t)(m0 >> 7) * K * HID_ : Bm;
  const int ct0 = ch * 10;
  const int nct = ch ? 9 : 10;      // tiles 0..9 / 10..18 (col 160..299)
  f32x4 acc[10];
#pragma unroll
  for (int t = 0; t < 10; ++t) acc[t] = f32x4{0.f, 0.f, 0.f, 0.f};

  for (int ks = 0; ks < K / 32; ++ks) {
    float4 a0 = *reinterpret_cast<const float4*>(Ap + ks * 32);
    float4 a1 = *reinterpret_cast<const float4*>(Ap + ks * 32 + 4);
    float av[8] = {a0.x, a0.y, a0.z, a0.w, a1.x, a1.y, a1.z, a1.w};
    bf16x8 ah, al;
#pragma unroll
    for (int j = 0; j < 8; ++j) {
      float v = av[j];
      __bf16 hv = (__bf16)v;
      ah[j] = hv;
      al[j] = (__bf16)(v - (float)hv);
    }
    const int kb = ks * 32 + (lane >> 4) * 8;
#pragma unroll
    for (int t = 0; t < 10; ++t) {
      if (t < nct) {
        const int col = (ct0 + t) * 16 + (lane & 15);
        const bool cv = col < HID_;
        const float* Bc = Bp + (size_t)kb * HID_ + col;
        float bv[8];
#pragma unroll
        for (int i = 0; i < 8; ++i) bv[i] = cv ? Bc[(size_t)i * HID_] : 0.f;
        bf16x8 bh, bl;
#pragma unroll
        for (int j = 0; j < 8; ++j) {
          float v = bv[j];
          __bf16 hv = (__bf16)v;
          bh[j] = hv;
          bl[j] = (__bf16)(v - (float)hv);
        }
        acc[t] = __builtin_amdgcn_mfma_f32_16x16x32_bf16(al, bh, acc[t], 0, 0, 0);
        acc[t] = __builtin_amdgcn_mfma_f32_16x16x32_bf16(ah, bl, acc[t], 0, 0, 0);
        acc[t] = __builtin_amdgcn_mfma_f32_16x16x32_bf16(ah, bh, acc[t], 0, 0, 0);
      }
    }
  }

  const int orow = m0 + (lane >> 4) * 4;
  const int ocol0 = (lane & 15);
#pragma unroll
  for (int t = 0; t < 10; ++t) {
    if (t < nct) {
      const int col = (ct0 + t) * 16 + ocol0;
      if (col < HID_) {
#pragma unroll
        for (int r = 0; r < 4; ++r) {
          float v = acc[t][r];
          if (ACT == 2) v = eluf(v);
          C[(size_t)(orow + r) * HID_ + col] = v;
        }
      }
    }
  }
}

// Split-K partial GEMM for small-M matmuls: grid (M/ROWS, KSPLIT).
template <int ROWS, int KSPLIT>
__global__ void gemm_skp(const float* __restrict__ A, const float* __restrict__ Bm,
                         float* __restrict__ P, int M, int K, int N) {
  const int c = threadIdx.x;
  const int r0 = blockIdx.x * ROWS;
  const int ks = blockIdx.y;
  if (c >= N) return;
  const int kchunk = (K + KSPLIT - 1) / KSPLIT;
  const int k0 = ks * kchunk;
  const int k1 = (k0 + kchunk < K) ? (k0 + kchunk) : K;
  float acc[ROWS];
#pragma unroll
  for (int r = 0; r < ROWS; ++r) acc[r] = 0.f;
  int k = k0;
  for (; k + 3 < k1; k += 4) {
    const float b0 = Bm[(size_t)(k + 0) * N + c];
    const float b1 = Bm[(size_t)(k + 1) * N + c];
    const float b2 = Bm[(size_t)(k + 2) * N + c];
    const float b3 = Bm[(size_t)(k + 3) * N + c];
#pragma unroll
    for (int r = 0; r < ROWS; ++r) {
      float4 a = ld4u(A + (size_t)(r0 + r) * K + k);
      acc[r] = fmaf(a.x, b0, acc[r]);
      acc[r] = fmaf(a.y, b1, acc[r]);
      acc[r] = fmaf(a.z, b2, acc[r]);
      acc[r] = fmaf(a.w, b3, acc[r]);
    }
  }
  for (; k < k1; ++k) {
    const float bv = Bm[(size_t)k * N + c];
#pragma unroll
    for (int r = 0; r < ROWS; ++r)
      acc[r] = fmaf(A[(size_t)(r0 + r) * K + k], bv, acc[r]);
  }
#pragma unroll
  for (int r = 0; r < ROWS; ++r)
    P[((size_t)ks * M + r0 + r) * N + c] = acc[r];
}

// Reduce split-K partials + bias + act. act: 0 none, 1 relu.
template <int KSPLIT>
__global__ void k_red(const float* __restrict__ P, const float* __restrict__ bias,
                      float* __restrict__ C, int M, int N, int ldc, int act) {
  const int idx = blockIdx.x * 256 + threadIdx.x;
  if (idx >= M * N) return;
  const int m = idx / N, c = idx - m * N;
  float v = 0.f;
#pragma unroll
  for (int p = 0; p < KSPLIT; ++p) v += P[(size_t)p * M * N + idx];
  if (bias) v += bias[c];
  if (act == 1) v = fmaxf(v, 0.f);
  C[(size_t)m * ldc + c] = v;
}

// K4: s2/d2 = Wh2 @ a_out halves. One wave per row.
__global__ __launch_bounds__(256) void k4_sd2(
    const float* __restrict__ Wh2, const float* __restrict__ ao,
    float* __restrict__ s2, float* __restrict__ d2) {
  const int lane = threadIdx.x & 63;
  const int row = blockIdx.x * 4 + (threadIdx.x >> 6);
  const float* wrow = Wh2 + (size_t)row * HID_;
  float as = 0.f, ad = 0.f;
  for (int c = lane; c < HID_; c += 64) {
    float v = wrow[c];
    as = fmaf(v, ao[c], as);
    ad = fmaf(v, ao[HID_ + c], ad);
  }
  as = wred_sum(as);
  ad = wred_sum(ad);
  if (lane == 0) { s2[row] = as; d2[row] = ad; }
}

// K5: attn2 probabilities p2[b,i,j]. One wave per row i.
__global__ __launch_bounds__(256) void k5_p2(
    const float* __restrict__ s2, const float* __restrict__ d2,
    const int* __restrict__ adj, float* __restrict__ p2) {
  const int lane = threadIdx.x & 63;
  const int row = blockIdx.x * 4 + (threadIdx.x >> 6);  // b*N+i
  const int b = row >> 7;
  float sv = s2[row];
  const float* drow = d2 + (size_t)b * N_;
  const int* arow = adj + (size_t)row * N_;
  float dv0 = drow[lane], dv1 = drow[64 + lane];
  int a0 = arow[lane], a1i = arow[64 + lane];
  float e0 = a0 > 0 ? lrelu(sv + dv0) : NEG_;
  float e1 = a1i > 0 ? lrelu(sv + dv1) : NEG_;
  float mx = wred_max(fmaxf(e0, e1));
  float x0 = expf(e0 - mx), x1 = expf(e1 - mx);
  float inv = 1.f / wred_sum(x0 + x1);
  p2[(size_t)row * N_ + lane] = x0 * inv;
  p2[(size_t)row * N_ + 64 + lane] = x1 * inv;
}

// K7: per-row max and log-sum-exp over 300 cols. One wave per row.
__global__ __launch_bounds__(256) void k7_lse(
    const float* __restrict__ ob, float* __restrict__ mx, float* __restrict__ ls) {
  const int lane = threadIdx.x & 63;
  const int row = blockIdx.x * 4 + (threadIdx.x >> 6);
  const float* orow = ob + (size_t)row * HID_;
  float v[5], m = -1e30f;
#pragma unroll
  for (int q = 0; q < 5; ++q) {
    int c = lane + q * 64;
    v[q] = (c < HID_) ? orow[c] : -1e30f;
    m = fmaxf(m, v[q]);
  }
  m = wred_max(m);
  float s = 0.f;
#pragma unroll
  for (int q = 0; q < 5; ++q) {
    int c = lane + q * 64;
    if (c < HID_) s += expf(v[q] - m);
  }
  s = wred_sum(s);
  if (lane == 0) { mx[row] = m; ls[row] = logf(s); }
}

// K8: gat_out[b,c] = mean_i (ob[b,i,c] - mx - ls). grid 256, block 320.
__global__ void k8_mean(const float* __restrict__ ob, const float* __restrict__ mx,
                        const float* __restrict__ ls, float* __restrict__ gat) {
  const int c = threadIdx.x;
  const int b = blockIdx.x;
  if (c >= HID_) return;
  float acc = 0.f;
  for (int i = 0; i < N_; ++i) {
    int row = b * N_ + i;
    acc += ob[(size_t)row * HID_ + c] - mx[row] - ls[row];
  }
  gat[(size_t)b * HID_ + c] = acc * (1.f / N_);
}

// out[b] = sigmoid(y[b,:] @ ffn_w2 + b2). One wave per row.
__global__ __launch_bounds__(256) void k_final(
    const float* __restrict__ y, const float* __restrict__ w2,
    const float* __restrict__ b2, float* __restrict__ out) {
  const int lane = threadIdx.x & 63;
  const int b = blockIdx.x * 4 + (threadIdx.x >> 6);
  float acc = 0.f;
  for (int c = lane; c < HID_; c += 64)
    acc = fmaf(y[(size_t)b * HID_ + c], w2[c], acc);
  acc = wred_sum(acc);
  if (lane == 0) out[b] = 1.f / (1.f + expf(-(acc + b2[0])));
}

extern "C" void kernel_launch(void* const* d_in, const int* in_sizes, int n_in,
                              void* d_out, int out_size, void* d_ws, size_t ws_size,
                              hipStream_t stream) {
  const float* atom  = (const float*)d_in[0];
  const float* fp    = (const float*)d_in[1];
  const float* Whead = (const float*)d_in[2];
  const float* ah    = (const float*)d_in[3];
  const float* Wout  = (const float*)d_in[4];
  const float* aout  = (const float*)d_in[5];
  const float* fc1w  = (const float*)d_in[6];
  const float* fc1b  = (const float*)d_in[7];
  const float* fc2w  = (const float*)d_in[8];
  const float* fc2b  = (const float*)d_in[9];
  const float* fgw   = (const float*)d_in[10];
  const float* fgb   = (const float*)d_in[11];
  const float* ffw   = (const float*)d_in[12];
  const float* ffb   = (const float*)d_in[13];
  const float* w1    = (const float*)d_in[14];
  const float* b1    = (const float*)d_in[15];
  const float* w2    = (const float*)d_in[16];
  const float* b2    = (const float*)d_in[17];
  const int*   adj   = (const int*)d_in[18];
  float* out = (float*)d_out;

  float* ws = (float*)d_ws;
  // Aliased layout (peak ~139 MB of floats):
  float* Wh   = ws;                       // 16,777,216   [K1 w, K2 r]
  float* Wh2  = ws;                       //  9,830,400   [K3 w .. K6 r]  (Wh dead)
  float* pbuf = ws;                       // <=1,048,576  [split-K partials; only
                                          //  live before k1 and after k8]
  float* p2   = ws + 9830400;             //  4,194,304   [K5 w, K6 r]
  float* sb   = ws + 16777216;            //    262,144
  float* db   = ws + 17039360;            //    262,144
  float* hb   = ws + 17301504;            // 16,777,216   [K2 w, K3 r]
  float* ob   = ws + 17301504;            //  9,830,400   [K6 w ..]  (hb dead)
  float* s2   = ws + 34078720;
  float* d2   = s2 + 32768;
  float* mxb  = d2 + 32768;
  float* lsb  = mxb + 32768;
  float* gat  = lsb + 32768;              //  76,800
  float* fpn1 = gat + 76800;              // 131,072
  float* fpn2 = fpn1 + 131072;            //  76,800
  float* xcat = fpn2 + 76800;             // 153,600
  float* yb   = xcat + 153600;            //  76,800

  // FPN branch (before k1 so pbuf aliasing of Wh region is safe)
  gemm_skp<4, 8><<<dim3(64, 8), 512, 0, stream>>>(fp, fc1w, pbuf, B_, FPD_, FP2_);
  k_red<8><<<512, 256, 0, stream>>>(pbuf, fc1b, fpn1, B_, FP2_, FP2_, 1);
  gemm_skp<4, 4><<<dim3(64, 4), 320, 0, stream>>>(fpn1, fc2w, pbuf, B_, FP2_, HID_);
  k_red<4><<<300, 256, 0, stream>>>(pbuf, fc2b, fpn2, B_, HID_, HID_, 0);

  // GAT stage 1
  k1_mfma<<<dim3(256, 8), 512, 0, stream>>>(atom, Whead, ah, Wh, sb, db);
  k2_attn1<<<2048, 512, 0, stream>>>(Wh, sb, db, adj, hb);

  // Wh2 = h @ W_out  (M=32768, K=512, N=300) — MFMA split-bf16
  gemm_mfma<512, 0, false><<<1024, 256, 0, stream>>>(hb, Wout, Wh2);

  // GAT stage 2
  k4_sd2<<<8192, 256, 0, stream>>>(Wh2, aout, s2, d2);
  k5_p2<<<8192, 256, 0, stream>>>(s2, d2, adj, p2);
  // ob = elu(p2 @ Wh2)  (M=32768, K=128, N=300, B batched per 128 rows)
  gemm_mfma<128, 2, true><<<1024, 256, 0, stream>>>(p2, Wh2, ob);
  k7_lse<<<8192, 256, 0, stream>>>(ob, mxb, lsb);
  k8_mean<<<256, 320, 0, stream>>>(ob, mxb, lsb, gat);

  // Head (after k8: entire low ws region dead -> pbuf reuse is safe)
  gemm_skp<4, 4><<<dim3(64, 4), 320, 0, stream>>>(gat, fgw, pbuf, B_, HID_, HID_);
  k_red<4><<<300, 256, 0, stream>>>(pbuf, fgb, xcat, B_, HID_, 2 * HID_, 1);
  gemm_skp<4, 4><<<dim3(64, 4), 320, 0, stream>>>(fpn2, ffw, pbuf, B_, HID_, HID_);
  k_red<4><<<300, 256, 0, stream>>>(pbuf, ffb, xcat + 300, B_, HID_, 2 * HID_, 1);
  gemm_skp<4, 4><<<dim3(64, 4), 320, 0, stream>>>(xcat, w1, pbuf, B_, 2 * HID_, HID_);
  k_red<4><<<300, 256, 0, stream>>>(pbuf, b1, yb, B_, HID_, HID_, 1);
  k_final<<<64, 256, 0, stream>>>(yb, w2, b2, out);
}